// Round 1
// baseline (1724.826 us; speedup 1.0000x reference)
//
#include <hip/hip_runtime.h>

// 2-layer GCN on MI355X. N nodes, E directed edges (+ implicit self loops).
// Layer l: out = scatter_col( (X W)[row] * norm ) + selfloop + bias
// norm[e] = dinv[row]*ew[e]*dinv[col], dinv = rsqrt(deg+1) (self loop weight 1)

constexpr int DIN = 128;

__global__ void deg_kernel(const int* __restrict__ col, const float* __restrict__ ew,
                           float* __restrict__ deg, int E) {
    int e = blockIdx.x * blockDim.x + threadIdx.x;
    if (e < E) atomicAdd(&deg[col[e]], ew[e]);
}

__global__ void dinv_kernel(float* deg, int N) {
    int n = blockIdx.x * blockDim.x + threadIdx.x;
    if (n < N) {
        float d = deg[n] + 1.0f;                 // + self loop weight
        deg[n] = (d > 0.0f) ? rsqrtf(d) : 0.0f;  // in-place deg -> dinv
    }
}

// Y[N,DOUT] = X[N,128] @ W[128,DOUT].  W staged in LDS; 256 threads;
// each thread computes one node x 4 outputs (float4).
template <int DOUT>
__global__ __launch_bounds__(256) void gemm_kernel(
        const float* __restrict__ X, const float* __restrict__ W,
        float* __restrict__ Y, int N) {
    constexpr int JG = DOUT / 4;       // float4 column groups
    constexpr int NSUB = 256 / JG;     // nodes per tile
    __shared__ float sW[DIN * DOUT];
    __shared__ float sX[NSUB * 132];   // +4 pad: conflict-free broadcast reads
    for (int i = threadIdx.x; i < DIN * DOUT / 4; i += 256)
        reinterpret_cast<float4*>(sW)[i] = reinterpret_cast<const float4*>(W)[i];
    const int tj = threadIdx.x % JG;
    const int tn = threadIdx.x / JG;
    const int ntiles = (N + NSUB - 1) / NSUB;
    for (int tile = blockIdx.x; tile < ntiles; tile += gridDim.x) {
        const int base = tile * NSUB;
        __syncthreads();  // also covers initial sW load
        for (int f = threadIdx.x; f < NSUB * 32; f += 256) {
            const int node = f / 32, kk = f % 32;
            float4 v = make_float4(0.f, 0.f, 0.f, 0.f);
            if (base + node < N)
                v = reinterpret_cast<const float4*>(X)[(size_t)(base + node) * 32 + kk];
            float* dst = &sX[node * 132 + kk * 4];
            dst[0] = v.x; dst[1] = v.y; dst[2] = v.z; dst[3] = v.w;
        }
        __syncthreads();
        float4 acc = make_float4(0.f, 0.f, 0.f, 0.f);
        const float* xr = &sX[tn * 132];
        #pragma unroll 8
        for (int k = 0; k < DIN; k++) {
            const float xv = xr[k];                           // LDS broadcast
            const float4 w4 = *reinterpret_cast<const float4*>(&sW[k * DOUT + tj * 4]);
            acc.x += xv * w4.x; acc.y += xv * w4.y;
            acc.z += xv * w4.z; acc.w += xv * w4.w;
        }
        const int node = base + tn;
        if (node < N)
            reinterpret_cast<float4*>(Y)[(size_t)node * JG + tj] = acc;
    }
}

// For each edge: dst[col] += src[row] * (dinv[row]*ew*dinv[col]).
// DOUT/4 threads per edge, float4 gather, 4 scalar atomics.
template <int DOUT>
__global__ void scatter_kernel(const int* __restrict__ row, const int* __restrict__ col,
        const float* __restrict__ ew, const float* __restrict__ dinv,
        const float* __restrict__ src, float* __restrict__ dst, int E) {
    constexpr int TPE = DOUT / 4;
    const long long gid = (long long)blockIdx.x * blockDim.x + threadIdx.x;
    const int e = (int)(gid / TPE);
    if (e >= E) return;
    const int lane = (int)(gid % TPE);
    const int r = row[e], c = col[e];
    const float nrm = dinv[r] * ew[e] * dinv[c];
    const float4 v = reinterpret_cast<const float4*>(src)[(size_t)r * TPE + lane];
    float* d = dst + (size_t)c * DOUT + (size_t)lane * 4;
    atomicAdd(d + 0, v.x * nrm);
    atomicAdd(d + 1, v.y * nrm);
    atomicAdd(d + 2, v.z * nrm);
    atomicAdd(d + 3, v.w * nrm);
}

// dst = (dst + src*dinv[n]^2 + bias)  [+ relu]   (self-loop term, no atomics)
template <int DOUT, bool RELU>
__global__ void finish_kernel(const float* __restrict__ src, const float* __restrict__ dinv,
        const float* __restrict__ bias, float* __restrict__ dst, int N) {
    constexpr int JG = DOUT / 4;
    const int gid = blockIdx.x * blockDim.x + threadIdx.x;
    if (gid >= N * JG) return;
    const int n = gid / JG, kk = gid % JG;
    const float di = dinv[n];
    const float sl = di * di;
    const float4 s = reinterpret_cast<const float4*>(src)[gid];
    const float4 b = reinterpret_cast<const float4*>(bias)[kk];
    float4 a = reinterpret_cast<const float4*>(dst)[gid];
    a.x += s.x * sl + b.x;
    a.y += s.y * sl + b.y;
    a.z += s.z * sl + b.z;
    a.w += s.w * sl + b.w;
    if (RELU) {
        a.x = fmaxf(a.x, 0.f); a.y = fmaxf(a.y, 0.f);
        a.z = fmaxf(a.z, 0.f); a.w = fmaxf(a.w, 0.f);
    }
    reinterpret_cast<float4*>(dst)[gid] = a;
}

extern "C" void kernel_launch(void* const* d_in, const int* in_sizes, int n_in,
                              void* d_out, int out_size, void* d_ws, size_t ws_size,
                              hipStream_t stream) {
    const float* x  = (const float*)d_in[0];
    const int*   ei = (const int*)d_in[1];   // [2,E] flat: rows then cols
    const float* ew = (const float*)d_in[2];
    const float* W1 = (const float*)d_in[3];
    const float* b1 = (const float*)d_in[4];
    const float* W2 = (const float*)d_in[5];
    const float* b2 = (const float*)d_in[6];
    const int N = in_sizes[0] / 128;
    const int E = in_sizes[1] / 2;
    const int* row = ei;
    const int* col = ei + E;

    float* ws   = (float*)d_ws;
    float* dinv = ws;                        // N floats (deg, then dinv in place)
    float* A    = ws + N;                    // N*128 floats (xw, then hw)
    float* B    = A + (size_t)N * 128;       // N*128 floats (agg1, then h)
    float* out  = (float*)d_out;

    hipMemsetAsync(dinv, 0, (size_t)N * sizeof(float), stream);
    hipMemsetAsync(B,    0, (size_t)N * 128 * sizeof(float), stream);
    hipMemsetAsync(out,  0, (size_t)N * 64 * sizeof(float), stream);

    deg_kernel<<<(E + 255) / 256, 256, 0, stream>>>(col, ew, dinv, E);
    dinv_kernel<<<(N + 255) / 256, 256, 0, stream>>>(dinv, N);

    // ---- layer 1: h = relu(Ahat @ (x W1) + b1)
    gemm_kernel<128><<<1024, 256, 0, stream>>>(x, W1, A, N);
    {
        const long long t = (long long)E * 32;
        scatter_kernel<128><<<(int)((t + 255) / 256), 256, 0, stream>>>(row, col, ew, dinv, A, B, E);
    }
    finish_kernel<128, true><<<(N * 32 + 255) / 256, 256, 0, stream>>>(A, dinv, b1, B, N);

    // ---- layer 2: out = Ahat @ (h W2) + b2
    gemm_kernel<64><<<1024, 256, 0, stream>>>(B, W2, A, N);
    {
        const long long t = (long long)E * 16;
        scatter_kernel<64><<<(int)((t + 255) / 256), 256, 0, stream>>>(row, col, ew, dinv, A, out, E);
    }
    finish_kernel<64, false><<<(N * 16 + 255) / 256, 256, 0, stream>>>(A, dinv, b2, out, N);
}

// Round 2
// 550.136 us; speedup vs baseline: 3.1353x; 3.1353x over previous
//
#include <hip/hip_runtime.h>

// 2-layer GCN, gather formulation.
// CSR-by-destination built on device per call; aggregation = register
// accumulate over incoming edges + fused self-loop/bias/relu.

constexpr int DIN = 128;

__global__ void deg_kernel(const int* __restrict__ col, const float* __restrict__ ew,
                           float* __restrict__ deg, int* __restrict__ cnt, int E) {
    int e = blockIdx.x * blockDim.x + threadIdx.x;
    if (e < E) {
        int c = col[e];
        atomicAdd(&deg[c], ew[e]);
        atomicAdd(&cnt[c], 1);
    }
}

__global__ void dinv_kernel(float* deg, int N) {
    int n = blockIdx.x * blockDim.x + threadIdx.x;
    if (n < N) {
        float d = deg[n] + 1.0f;                 // + self loop weight
        deg[n] = (d > 0.0f) ? rsqrtf(d) : 0.0f;  // in-place deg -> dinv
    }
}

// Single-block exclusive scan of cnt[N] -> rowptr[N+1], also fills cursor[N].
__global__ __launch_bounds__(1024) void scan_kernel(const int* __restrict__ cnt,
        int* __restrict__ rowptr, int* __restrict__ cursor, int N) {
    __shared__ int ssum[1024];
    const int t = threadIdx.x;
    const int chunk = (N + 1023) / 1024;
    const int start = t * chunk;
    const int end = min(start + chunk, N);
    int s = 0;
    for (int i = start; i < end; i++) s += cnt[i];
    ssum[t] = s;
    __syncthreads();
    for (int off = 1; off < 1024; off <<= 1) {
        int v = ssum[t];
        int add = (t >= off) ? ssum[t - off] : 0;
        __syncthreads();
        ssum[t] = v + add;
        __syncthreads();
    }
    int excl = (t == 0) ? 0 : ssum[t - 1];
    for (int i = start; i < end; i++) {
        rowptr[i] = excl;
        cursor[i] = excl;
        excl += cnt[i];
    }
    if (t == 0) rowptr[N] = ssum[1023];
}

// Scatter edges into CSR slots (order within a node is arbitrary; sum is
// permutation-invariant up to f32 rounding, well under threshold).
__global__ void fill_kernel(const int* __restrict__ row, const int* __restrict__ col,
        const float* __restrict__ ew, const float* __restrict__ dinv,
        int* __restrict__ cursor, int* __restrict__ csr_src, float* __restrict__ csr_w, int E) {
    int e = blockIdx.x * blockDim.x + threadIdx.x;
    if (e < E) {
        const int c = col[e], r = row[e];
        const int p = atomicAdd(&cursor[c], 1);
        csr_src[p] = r;
        csr_w[p] = ew[e] * dinv[r];   // premultiply source-side norm
    }
}

// Y[N,DOUT] = X[N,128] @ W[128,DOUT].  W staged in LDS.
template <int DOUT>
__global__ __launch_bounds__(256) void gemm_kernel(
        const float* __restrict__ X, const float* __restrict__ W,
        float* __restrict__ Y, int N) {
    constexpr int JG = DOUT / 4;
    constexpr int NSUB = 256 / JG;
    __shared__ float sW[DIN * DOUT];
    __shared__ float sX[NSUB * 132];
    for (int i = threadIdx.x; i < DIN * DOUT / 4; i += 256)
        reinterpret_cast<float4*>(sW)[i] = reinterpret_cast<const float4*>(W)[i];
    const int tj = threadIdx.x % JG;
    const int tn = threadIdx.x / JG;
    const int ntiles = (N + NSUB - 1) / NSUB;
    for (int tile = blockIdx.x; tile < ntiles; tile += gridDim.x) {
        const int base = tile * NSUB;
        __syncthreads();
        for (int f = threadIdx.x; f < NSUB * 32; f += 256) {
            const int node = f / 32, kk = f % 32;
            float4 v = make_float4(0.f, 0.f, 0.f, 0.f);
            if (base + node < N)
                v = reinterpret_cast<const float4*>(X)[(size_t)(base + node) * 32 + kk];
            float* dst = &sX[node * 132 + kk * 4];
            dst[0] = v.x; dst[1] = v.y; dst[2] = v.z; dst[3] = v.w;
        }
        __syncthreads();
        float4 acc = make_float4(0.f, 0.f, 0.f, 0.f);
        const float* xr = &sX[tn * 132];
        #pragma unroll 8
        for (int k = 0; k < DIN; k++) {
            const float xv = xr[k];
            const float4 w4 = *reinterpret_cast<const float4*>(&sW[k * DOUT + tj * 4]);
            acc.x += xv * w4.x; acc.y += xv * w4.y;
            acc.z += xv * w4.z; acc.w += xv * w4.w;
        }
        const int node = base + tn;
        if (node < N)
            reinterpret_cast<float4*>(Y)[(size_t)node * JG + tj] = acc;
    }
}

// Gather-aggregate per destination node; fused self-loop + bias (+relu).
// TPE = DOUT/4 lanes per node, each owns one float4 of the feature vector.
template <int DOUT, bool RELU>
__global__ __launch_bounds__(256) void agg_kernel(
        const int* __restrict__ rowptr, const int* __restrict__ csr_src,
        const float* __restrict__ csr_w, const float* __restrict__ dinv,
        const float* __restrict__ src, const float* __restrict__ bias,
        float* __restrict__ dst, int N) {
    constexpr int TPE = DOUT / 4;
    const long long gid = (long long)blockIdx.x * blockDim.x + threadIdx.x;
    const int c = (int)(gid / TPE);
    if (c >= N) return;
    const int lane = (int)(gid % TPE);
    const float di = dinv[c];
    // self-loop term: src[c] * di*di
    float4 sv = reinterpret_cast<const float4*>(src)[(size_t)c * TPE + lane];
    const float sl = di * di;
    float4 acc;
    acc.x = sv.x * sl; acc.y = sv.y * sl; acc.z = sv.z * sl; acc.w = sv.w * sl;
    const int e0 = rowptr[c], e1 = rowptr[c + 1];
    for (int e = e0; e < e1; e++) {
        const int s = csr_src[e];
        const float w = csr_w[e] * di;          // (ew*dinv[src]) * dinv[c]
        const float4 v = reinterpret_cast<const float4*>(src)[(size_t)s * TPE + lane];
        acc.x += v.x * w; acc.y += v.y * w;
        acc.z += v.z * w; acc.w += v.w * w;
    }
    const float4 b = reinterpret_cast<const float4*>(bias)[lane];
    acc.x += b.x; acc.y += b.y; acc.z += b.z; acc.w += b.w;
    if (RELU) {
        acc.x = fmaxf(acc.x, 0.f); acc.y = fmaxf(acc.y, 0.f);
        acc.z = fmaxf(acc.z, 0.f); acc.w = fmaxf(acc.w, 0.f);
    }
    reinterpret_cast<float4*>(dst)[(size_t)c * TPE + lane] = acc;
}

extern "C" void kernel_launch(void* const* d_in, const int* in_sizes, int n_in,
                              void* d_out, int out_size, void* d_ws, size_t ws_size,
                              hipStream_t stream) {
    const float* x  = (const float*)d_in[0];
    const int*   ei = (const int*)d_in[1];   // [2,E] flat: rows then cols
    const float* ew = (const float*)d_in[2];
    const float* W1 = (const float*)d_in[3];
    const float* b1 = (const float*)d_in[4];
    const float* W2 = (const float*)d_in[5];
    const float* b2 = (const float*)d_in[6];
    const int N = in_sizes[0] / 128;
    const int E = in_sizes[1] / 2;
    const int* row = ei;
    const int* col = ei + E;

    // workspace layout (floats/ints, 4B each):
    // dinv[N] | A[N*128] | B[N*128] | cnt[N] | rowptr[N+1] | cursor[N] |
    // csr_src[E] | csr_w[E]
    float* ws     = (float*)d_ws;
    float* dinv   = ws;
    float* A      = ws + N;
    float* B      = A + (size_t)N * 128;
    int*   cnt    = (int*)(B + (size_t)N * 128);
    int*   rowptr = cnt + N;
    int*   cursor = rowptr + (N + 1);
    int*   csr_src= cursor + N;
    float* csr_w  = (float*)(csr_src + E);
    float* out    = (float*)d_out;

    hipMemsetAsync(dinv, 0, (size_t)N * sizeof(float), stream);
    hipMemsetAsync(cnt,  0, (size_t)N * sizeof(int), stream);

    deg_kernel<<<(E + 255) / 256, 256, 0, stream>>>(col, ew, dinv, cnt, E);
    dinv_kernel<<<(N + 255) / 256, 256, 0, stream>>>(dinv, N);
    scan_kernel<<<1, 1024, 0, stream>>>(cnt, rowptr, cursor, N);
    fill_kernel<<<(E + 255) / 256, 256, 0, stream>>>(row, col, ew, dinv, cursor,
                                                     csr_src, csr_w, E);

    // ---- layer 1: B = relu(Ahat @ (x W1) + b1)
    gemm_kernel<128><<<1024, 256, 0, stream>>>(x, W1, A, N);
    {
        const long long t = (long long)N * 32;
        agg_kernel<128, true><<<(int)((t + 255) / 256), 256, 0, stream>>>(
            rowptr, csr_src, csr_w, dinv, A, b1, B, N);
    }

    // ---- layer 2: out = Ahat @ (B W2) + b2
    gemm_kernel<64><<<1024, 256, 0, stream>>>(B, W2, A, N);
    {
        const long long t = (long long)N * 16;
        agg_kernel<64, false><<<(int)((t + 255) / 256), 256, 0, stream>>>(
            rowptr, csr_src, csr_w, dinv, A, b2, out, N);
    }
}

// Round 3
// 336.113 us; speedup vs baseline: 5.1317x; 1.6368x over previous
//
#include <hip/hip_runtime.h>

// 2-layer GCN, gather formulation.
// CSR-by-destination built on device per call; aggregation = register
// accumulate over incoming edges + fused self-loop/bias/relu.

constexpr int DIN = 128;
constexpr int SCAN_BLOCKS = 256;   // multi-block scan geometry

__global__ void deg_kernel(const int* __restrict__ col, const float* __restrict__ ew,
                           float* __restrict__ deg, int* __restrict__ cnt, int E) {
    int e = blockIdx.x * blockDim.x + threadIdx.x;
    if (e < E) {
        int c = col[e];
        atomicAdd(&deg[c], ew[e]);
        atomicAdd(&cnt[c], 1);
    }
}

__global__ void dinv_kernel(float* deg, int N) {
    int n = blockIdx.x * blockDim.x + threadIdx.x;
    if (n < N) {
        float d = deg[n] + 1.0f;                 // + self loop weight
        deg[n] = (d > 0.0f) ? rsqrtf(d) : 0.0f;  // in-place deg -> dinv
    }
}

// ---- 3-pass scan: cnt[N] -> exclusive rowptr[N+1] (+cursor copy) ----
// pass 1: per-block sum of its chunk -> partial[b]
__global__ __launch_bounds__(256) void scan_part_kernel(
        const int* __restrict__ cnt, int* __restrict__ partial, int N) {
    const int T = SCAN_BLOCKS * 256;
    const int chunk = (N + T - 1) / T;
    const int j = blockIdx.x * 256 + threadIdx.x;
    const int s = j * chunk, e = min(s + chunk, N);
    int acc = 0;
    for (int i = s; i < e; i++) acc += cnt[i];
    __shared__ int red[256];
    red[threadIdx.x] = acc;
    __syncthreads();
    for (int off = 128; off > 0; off >>= 1) {
        if (threadIdx.x < off) red[threadIdx.x] += red[threadIdx.x + off];
        __syncthreads();
    }
    if (threadIdx.x == 0) partial[blockIdx.x] = red[0];
}

// pass 2: one block scans the SCAN_BLOCKS partials -> exclusive offsets
__global__ __launch_bounds__(256) void scan_tops_kernel(int* __restrict__ partial) {
    __shared__ int sh[256];
    const int t = threadIdx.x;
    int v = (t < SCAN_BLOCKS) ? partial[t] : 0;
    sh[t] = v;
    __syncthreads();
    for (int off = 1; off < 256; off <<= 1) {
        int x = sh[t];
        int a = (t >= off) ? sh[t - off] : 0;
        __syncthreads();
        sh[t] = x + a;
        __syncthreads();
    }
    if (t < SCAN_BLOCKS) partial[t] = (t == 0) ? 0 : sh[t - 1];
}

// pass 3: recompute thread sums, block-exclusive-scan them, write rowptr+cursor
__global__ __launch_bounds__(256) void scan_write_kernel(
        const int* __restrict__ cnt, const int* __restrict__ partial,
        int* __restrict__ rowptr, int* __restrict__ cursor, int N) {
    const int T = SCAN_BLOCKS * 256;
    const int chunk = (N + T - 1) / T;
    const int j = blockIdx.x * 256 + threadIdx.x;
    const int s = j * chunk, e = min(s + chunk, N);
    int acc = 0;
    for (int i = s; i < e; i++) acc += cnt[i];
    __shared__ int sh[256];
    const int t = threadIdx.x;
    sh[t] = acc;
    __syncthreads();
    for (int off = 1; off < 256; off <<= 1) {
        int x = sh[t];
        int a = (t >= off) ? sh[t - off] : 0;
        __syncthreads();
        sh[t] = x + a;
        __syncthreads();
    }
    int excl = partial[blockIdx.x] + ((t == 0) ? 0 : sh[t - 1]);
    for (int i = s; i < e; i++) {
        rowptr[i] = excl;
        cursor[i] = excl;
        excl += cnt[i];
    }
    if (j == T - 1) rowptr[N] = excl;   // last thread's excl == total E
}

// Scatter edges into CSR slots (order within a node arbitrary; f32 sum
// permutation differences are far under the threshold).
__global__ void fill_kernel(const int* __restrict__ row, const int* __restrict__ col,
        const float* __restrict__ ew, const float* __restrict__ dinv,
        int* __restrict__ cursor, int* __restrict__ csr_src, float* __restrict__ csr_w, int E) {
    int e = blockIdx.x * blockDim.x + threadIdx.x;
    if (e < E) {
        const int c = col[e], r = row[e];
        const int p = atomicAdd(&cursor[c], 1);
        csr_src[p] = r;
        csr_w[p] = ew[e] * dinv[r];   // premultiply source-side norm
    }
}

// Y[N,DOUT] = X[N,128] @ W[128,DOUT].  W staged in LDS.
template <int DOUT>
__global__ __launch_bounds__(256) void gemm_kernel(
        const float* __restrict__ X, const float* __restrict__ W,
        float* __restrict__ Y, int N) {
    constexpr int JG = DOUT / 4;
    constexpr int NSUB = 256 / JG;
    __shared__ float sW[DIN * DOUT];
    __shared__ float sX[NSUB * 132];
    for (int i = threadIdx.x; i < DIN * DOUT / 4; i += 256)
        reinterpret_cast<float4*>(sW)[i] = reinterpret_cast<const float4*>(W)[i];
    const int tj = threadIdx.x % JG;
    const int tn = threadIdx.x / JG;
    const int ntiles = (N + NSUB - 1) / NSUB;
    for (int tile = blockIdx.x; tile < ntiles; tile += gridDim.x) {
        const int base = tile * NSUB;
        __syncthreads();
        for (int f = threadIdx.x; f < NSUB * 32; f += 256) {
            const int node = f / 32, kk = f % 32;
            float4 v = make_float4(0.f, 0.f, 0.f, 0.f);
            if (base + node < N)
                v = reinterpret_cast<const float4*>(X)[(size_t)(base + node) * 32 + kk];
            float* dst = &sX[node * 132 + kk * 4];
            dst[0] = v.x; dst[1] = v.y; dst[2] = v.z; dst[3] = v.w;
        }
        __syncthreads();
        float4 acc = make_float4(0.f, 0.f, 0.f, 0.f);
        const float* xr = &sX[tn * 132];
        #pragma unroll 8
        for (int k = 0; k < DIN; k++) {
            const float xv = xr[k];
            const float4 w4 = *reinterpret_cast<const float4*>(&sW[k * DOUT + tj * 4]);
            acc.x += xv * w4.x; acc.y += xv * w4.y;
            acc.z += xv * w4.z; acc.w += xv * w4.w;
        }
        const int node = base + tn;
        if (node < N)
            reinterpret_cast<float4*>(Y)[(size_t)node * JG + tj] = acc;
    }
}

// Gather-aggregate per destination node; fused self-loop + bias (+relu).
template <int DOUT, bool RELU>
__global__ __launch_bounds__(256) void agg_kernel(
        const int* __restrict__ rowptr, const int* __restrict__ csr_src,
        const float* __restrict__ csr_w, const float* __restrict__ dinv,
        const float* __restrict__ src, const float* __restrict__ bias,
        float* __restrict__ dst, int N) {
    constexpr int TPE = DOUT / 4;
    const long long gid = (long long)blockIdx.x * blockDim.x + threadIdx.x;
    const int c = (int)(gid / TPE);
    if (c >= N) return;
    const int lane = (int)(gid % TPE);
    const float di = dinv[c];
    float4 sv = reinterpret_cast<const float4*>(src)[(size_t)c * TPE + lane];
    const float sl = di * di;
    float4 acc;
    acc.x = sv.x * sl; acc.y = sv.y * sl; acc.z = sv.z * sl; acc.w = sv.w * sl;
    const int e0 = rowptr[c], e1 = rowptr[c + 1];
    for (int e = e0; e < e1; e++) {
        const int s = csr_src[e];
        const float w = csr_w[e] * di;          // (ew*dinv[src]) * dinv[c]
        const float4 v = reinterpret_cast<const float4*>(src)[(size_t)s * TPE + lane];
        acc.x += v.x * w; acc.y += v.y * w;
        acc.z += v.z * w; acc.w += v.w * w;
    }
    const float4 b = reinterpret_cast<const float4*>(bias)[lane];
    acc.x += b.x; acc.y += b.y; acc.z += b.z; acc.w += b.w;
    if (RELU) {
        acc.x = fmaxf(acc.x, 0.f); acc.y = fmaxf(acc.y, 0.f);
        acc.z = fmaxf(acc.z, 0.f); acc.w = fmaxf(acc.w, 0.f);
    }
    reinterpret_cast<float4*>(dst)[(size_t)c * TPE + lane] = acc;
}

extern "C" void kernel_launch(void* const* d_in, const int* in_sizes, int n_in,
                              void* d_out, int out_size, void* d_ws, size_t ws_size,
                              hipStream_t stream) {
    const float* x  = (const float*)d_in[0];
    const int*   ei = (const int*)d_in[1];   // [2,E] flat: rows then cols
    const float* ew = (const float*)d_in[2];
    const float* W1 = (const float*)d_in[3];
    const float* b1 = (const float*)d_in[4];
    const float* W2 = (const float*)d_in[5];
    const float* b2 = (const float*)d_in[6];
    const int N = in_sizes[0] / 128;
    const int E = in_sizes[1] / 2;
    const int* row = ei;
    const int* col = ei + E;

    // workspace layout (4B units):
    // dinv[N] | A[N*128] | B[N*128] | cnt[N] | rowptr[N+1] | cursor[N] |
    // partial[SCAN_BLOCKS] | csr_src[E] | csr_w[E]
    float* ws     = (float*)d_ws;
    float* dinv   = ws;
    float* A      = ws + N;
    float* B      = A + (size_t)N * 128;
    int*   cnt    = (int*)(B + (size_t)N * 128);
    int*   rowptr = cnt + N;
    int*   cursor = rowptr + (N + 1);
    int*   partial= cursor + N;
    int*   csr_src= partial + SCAN_BLOCKS;
    float* csr_w  = (float*)(csr_src + E);
    float* out    = (float*)d_out;

    hipMemsetAsync(dinv, 0, (size_t)N * sizeof(float), stream);
    hipMemsetAsync(cnt,  0, (size_t)N * sizeof(int), stream);

    deg_kernel<<<(E + 255) / 256, 256, 0, stream>>>(col, ew, dinv, cnt, E);
    dinv_kernel<<<(N + 255) / 256, 256, 0, stream>>>(dinv, N);
    scan_part_kernel<<<SCAN_BLOCKS, 256, 0, stream>>>(cnt, partial, N);
    scan_tops_kernel<<<1, 256, 0, stream>>>(partial);
    scan_write_kernel<<<SCAN_BLOCKS, 256, 0, stream>>>(cnt, partial, rowptr, cursor, N);
    fill_kernel<<<(E + 255) / 256, 256, 0, stream>>>(row, col, ew, dinv, cursor,
                                                     csr_src, csr_w, E);

    // ---- layer 1: B = relu(Ahat @ (x W1) + b1)
    gemm_kernel<128><<<1024, 256, 0, stream>>>(x, W1, A, N);
    {
        const long long t = (long long)N * 32;
        agg_kernel<128, true><<<(int)((t + 255) / 256), 256, 0, stream>>>(
            rowptr, csr_src, csr_w, dinv, A, b1, B, N);
    }

    // ---- layer 2: out = Ahat @ (B W2) + b2
    gemm_kernel<64><<<1024, 256, 0, stream>>>(B, W2, A, N);
    {
        const long long t = (long long)N * 16;
        agg_kernel<64, false><<<(int)((t + 255) / 256), 256, 0, stream>>>(
            rowptr, csr_src, csr_w, dinv, A, b2, out, N);
    }
}

// Round 4
// 299.125 us; speedup vs baseline: 5.7662x; 1.1237x over previous
//
#include <hip/hip_runtime.h>

// 2-layer GCN, gather formulation + register-tiled f32 GEMM.

constexpr int DIN = 128;
constexpr int SCAN_BLOCKS = 256;

__global__ void deg_kernel(const int* __restrict__ col, const float* __restrict__ ew,
                           float* __restrict__ deg, int* __restrict__ cnt, int E) {
    int e = blockIdx.x * blockDim.x + threadIdx.x;
    if (e < E) {
        int c = col[e];
        atomicAdd(&deg[c], ew[e]);
        atomicAdd(&cnt[c], 1);
    }
}

__global__ void dinv_kernel(float* deg, int N) {
    int n = blockIdx.x * blockDim.x + threadIdx.x;
    if (n < N) {
        float d = deg[n] + 1.0f;
        deg[n] = (d > 0.0f) ? rsqrtf(d) : 0.0f;
    }
}

// ---- 3-pass scan: cnt[N] -> exclusive rowptr[N+1] (+cursor copy) ----
__global__ __launch_bounds__(256) void scan_part_kernel(
        const int* __restrict__ cnt, int* __restrict__ partial, int N) {
    const int T = SCAN_BLOCKS * 256;
    const int chunk = (N + T - 1) / T;
    const int j = blockIdx.x * 256 + threadIdx.x;
    const int s = j * chunk, e = min(s + chunk, N);
    int acc = 0;
    for (int i = s; i < e; i++) acc += cnt[i];
    __shared__ int red[256];
    red[threadIdx.x] = acc;
    __syncthreads();
    for (int off = 128; off > 0; off >>= 1) {
        if (threadIdx.x < off) red[threadIdx.x] += red[threadIdx.x + off];
        __syncthreads();
    }
    if (threadIdx.x == 0) partial[blockIdx.x] = red[0];
}

__global__ __launch_bounds__(256) void scan_tops_kernel(int* __restrict__ partial) {
    __shared__ int sh[256];
    const int t = threadIdx.x;
    int v = (t < SCAN_BLOCKS) ? partial[t] : 0;
    sh[t] = v;
    __syncthreads();
    for (int off = 1; off < 256; off <<= 1) {
        int x = sh[t];
        int a = (t >= off) ? sh[t - off] : 0;
        __syncthreads();
        sh[t] = x + a;
        __syncthreads();
    }
    if (t < SCAN_BLOCKS) partial[t] = (t == 0) ? 0 : sh[t - 1];
}

__global__ __launch_bounds__(256) void scan_write_kernel(
        const int* __restrict__ cnt, const int* __restrict__ partial,
        int* __restrict__ rowptr, int* __restrict__ cursor, int N) {
    const int T = SCAN_BLOCKS * 256;
    const int chunk = (N + T - 1) / T;
    const int j = blockIdx.x * 256 + threadIdx.x;
    const int s = j * chunk, e = min(s + chunk, N);
    int acc = 0;
    for (int i = s; i < e; i++) acc += cnt[i];
    __shared__ int sh[256];
    const int t = threadIdx.x;
    sh[t] = acc;
    __syncthreads();
    for (int off = 1; off < 256; off <<= 1) {
        int x = sh[t];
        int a = (t >= off) ? sh[t - off] : 0;
        __syncthreads();
        sh[t] = x + a;
        __syncthreads();
    }
    int excl = partial[blockIdx.x] + ((t == 0) ? 0 : sh[t - 1]);
    for (int i = s; i < e; i++) {
        rowptr[i] = excl;
        cursor[i] = excl;
        excl += cnt[i];
    }
    if (j == T - 1) rowptr[N] = excl;
}

__global__ void fill_kernel(const int* __restrict__ row, const int* __restrict__ col,
        const float* __restrict__ ew, const float* __restrict__ dinv,
        int* __restrict__ cursor, int* __restrict__ csr_src, float* __restrict__ csr_w, int E) {
    int e = blockIdx.x * blockDim.x + threadIdx.x;
    if (e < E) {
        const int c = col[e], r = row[e];
        const int p = atomicAdd(&cursor[c], 1);
        csr_src[p] = r;
        csr_w[p] = ew[e] * dinv[r];
    }
}

// Register-tiled GEMM: Y[N,DOUT] = X[N,128] @ W[128,DOUT].
// grid.x = node tiles (128 nodes), grid.y = col tiles (64 cols).
// 256 threads: tn=tid>>3 (32 groups x 4 nodes), tj=tid&7 (8 groups x 8 cols).
// Per k: 4 ds_read_b32 (X, 2-way free via ldx=66) + 2 ds_read_b128 (W) -> 32 FMA.
template <int DOUT>
__global__ __launch_bounds__(256, 2) void gemm_kernel(
        const float* __restrict__ X, const float* __restrict__ W,
        float* __restrict__ Y, int N) {
    constexpr int LDX = 66;                 // 64-k slab + 2 pad (bank spread)
    __shared__ float sW[DIN * 64];          // full-K W column slab (32 KB)
    __shared__ float sX[128 * LDX];         // 128-node x 64-k slab (33 KB)
    const int tid = threadIdx.x;
    const int cb = blockIdx.y * 64;
    const int base = blockIdx.x * 128;

    // stage W[0:128][cb:cb+64] (one-time, L2-resident source)
    {
        const int a = tid & 15, b = tid >> 4;
        #pragma unroll
        for (int p = 0; p < 8; p++) {
            const int k = p * 16 + b;
            const float4 w = *reinterpret_cast<const float4*>(
                &W[(size_t)k * DOUT + cb + a * 4]);
            *reinterpret_cast<float4*>(&sW[k * 64 + a * 4]) = w;
        }
    }

    const int tn = tid >> 3;   // node group [0,32)
    const int tj = tid & 7;    // col group  [0,8)
    float acc[4][8];
    #pragma unroll
    for (int i = 0; i < 4; i++)
        #pragma unroll
        for (int j = 0; j < 8; j++) acc[i][j] = 0.f;

    for (int k0 = 0; k0 < DIN; k0 += 64) {
        __syncthreads();   // protect sX (prev readers) + sW staging on first iter
        {   // stage X[base..base+127][k0..k0+63]; coalesced 256B/group reads
            const int a = tid & 15, b = tid >> 4;
            #pragma unroll
            for (int p = 0; p < 8; p++) {
                const int node = p * 16 + b;
                float4 v = make_float4(0.f, 0.f, 0.f, 0.f);
                if (base + node < N)
                    v = *reinterpret_cast<const float4*>(
                        &X[(size_t)(base + node) * DIN + k0 + a * 4]);
                float* d = &sX[node * LDX + a * 4];   // 8B-aligned (odd rows)
                *reinterpret_cast<float2*>(d)     = make_float2(v.x, v.y);
                *reinterpret_cast<float2*>(d + 2) = make_float2(v.z, v.w);
            }
        }
        __syncthreads();
        #pragma unroll 8
        for (int kk = 0; kk < 64; kk++) {
            const float4 w0 = *reinterpret_cast<const float4*>(&sW[(k0 + kk) * 64 + tj * 8]);
            const float4 w1 = *reinterpret_cast<const float4*>(&sW[(k0 + kk) * 64 + tj * 8 + 4]);
            #pragma unroll
            for (int i = 0; i < 4; i++) {
                const float xv = sX[(tn * 4 + i) * LDX + kk];
                acc[i][0] += xv * w0.x; acc[i][1] += xv * w0.y;
                acc[i][2] += xv * w0.z; acc[i][3] += xv * w0.w;
                acc[i][4] += xv * w1.x; acc[i][5] += xv * w1.y;
                acc[i][6] += xv * w1.z; acc[i][7] += xv * w1.w;
            }
        }
    }
    #pragma unroll
    for (int i = 0; i < 4; i++) {
        const int node = base + tn * 4 + i;
        if (node < N) {
            float* y = &Y[(size_t)node * DOUT + cb + tj * 8];
            *reinterpret_cast<float4*>(y) =
                make_float4(acc[i][0], acc[i][1], acc[i][2], acc[i][3]);
            *reinterpret_cast<float4*>(y + 4) =
                make_float4(acc[i][4], acc[i][5], acc[i][6], acc[i][7]);
        }
    }
}

// Gather-aggregate per destination node; fused self-loop + bias (+relu).
template <int DOUT, bool RELU>
__global__ __launch_bounds__(256) void agg_kernel(
        const int* __restrict__ rowptr, const int* __restrict__ csr_src,
        const float* __restrict__ csr_w, const float* __restrict__ dinv,
        const float* __restrict__ src, const float* __restrict__ bias,
        float* __restrict__ dst, int N) {
    constexpr int TPE = DOUT / 4;
    const long long gid = (long long)blockIdx.x * blockDim.x + threadIdx.x;
    const int c = (int)(gid / TPE);
    if (c >= N) return;
    const int lane = (int)(gid % TPE);
    const float di = dinv[c];
    float4 sv = reinterpret_cast<const float4*>(src)[(size_t)c * TPE + lane];
    const float sl = di * di;
    float4 acc;
    acc.x = sv.x * sl; acc.y = sv.y * sl; acc.z = sv.z * sl; acc.w = sv.w * sl;
    const int e0 = rowptr[c], e1 = rowptr[c + 1];
    for (int e = e0; e < e1; e++) {
        const int s = csr_src[e];
        const float w = csr_w[e] * di;
        const float4 v = reinterpret_cast<const float4*>(src)[(size_t)s * TPE + lane];
        acc.x += v.x * w; acc.y += v.y * w;
        acc.z += v.z * w; acc.w += v.w * w;
    }
    const float4 b = reinterpret_cast<const float4*>(bias)[lane];
    acc.x += b.x; acc.y += b.y; acc.z += b.z; acc.w += b.w;
    if (RELU) {
        acc.x = fmaxf(acc.x, 0.f); acc.y = fmaxf(acc.y, 0.f);
        acc.z = fmaxf(acc.z, 0.f); acc.w = fmaxf(acc.w, 0.f);
    }
    reinterpret_cast<float4*>(dst)[(size_t)c * TPE + lane] = acc;
}

extern "C" void kernel_launch(void* const* d_in, const int* in_sizes, int n_in,
                              void* d_out, int out_size, void* d_ws, size_t ws_size,
                              hipStream_t stream) {
    const float* x  = (const float*)d_in[0];
    const int*   ei = (const int*)d_in[1];
    const float* ew = (const float*)d_in[2];
    const float* W1 = (const float*)d_in[3];
    const float* b1 = (const float*)d_in[4];
    const float* W2 = (const float*)d_in[5];
    const float* b2 = (const float*)d_in[6];
    const int N = in_sizes[0] / 128;
    const int E = in_sizes[1] / 2;
    const int* row = ei;
    const int* col = ei + E;

    float* ws     = (float*)d_ws;
    float* dinv   = ws;
    float* A      = ws + N;
    float* B      = A + (size_t)N * 128;
    int*   cnt    = (int*)(B + (size_t)N * 128);
    int*   rowptr = cnt + N;
    int*   cursor = rowptr + (N + 1);
    int*   partial= cursor + N;
    int*   csr_src= partial + SCAN_BLOCKS;
    float* csr_w  = (float*)(csr_src + E);
    float* out    = (float*)d_out;

    hipMemsetAsync(dinv, 0, (size_t)N * sizeof(float), stream);
    hipMemsetAsync(cnt,  0, (size_t)N * sizeof(int), stream);

    deg_kernel<<<(E + 255) / 256, 256, 0, stream>>>(col, ew, dinv, cnt, E);
    dinv_kernel<<<(N + 255) / 256, 256, 0, stream>>>(dinv, N);
    scan_part_kernel<<<SCAN_BLOCKS, 256, 0, stream>>>(cnt, partial, N);
    scan_tops_kernel<<<1, 256, 0, stream>>>(partial);
    scan_write_kernel<<<SCAN_BLOCKS, 256, 0, stream>>>(cnt, partial, rowptr, cursor, N);
    fill_kernel<<<(E + 255) / 256, 256, 0, stream>>>(row, col, ew, dinv, cursor,
                                                     csr_src, csr_w, E);

    const int ntiles = (N + 127) / 128;

    // ---- layer 1: B = relu(Ahat @ (x W1) + b1)
    {
        dim3 grid(ntiles, 128 / 64);
        gemm_kernel<128><<<grid, 256, 0, stream>>>(x, W1, A, N);
        const long long t = (long long)N * 32;
        agg_kernel<128, true><<<(int)((t + 255) / 256), 256, 0, stream>>>(
            rowptr, csr_src, csr_w, dinv, A, b1, B, N);
    }

    // ---- layer 2: out = Ahat @ (B W2) + b2
    {
        dim3 grid(ntiles, 64 / 64);
        gemm_kernel<64><<<grid, 256, 0, stream>>>(B, W2, A, N);
        const long long t = (long long)N * 16;
        agg_kernel<64, false><<<(int)((t + 255) / 256), 256, 0, stream>>>(
            rowptr, csr_src, csr_w, dinv, A, b2, out, N);
    }
}

// Round 5
// 243.284 us; speedup vs baseline: 7.0898x; 1.2295x over previous
//
#include <hip/hip_runtime.h>

// 2-layer GCN: CSR-by-dest gather aggregation + bf16 MFMA GEMMs.

constexpr int DIN = 128;
constexpr int SCAN_BLOCKS = 256;

typedef __attribute__((ext_vector_type(8))) short short8;   // 8 bf16 (4 VGPR)
typedef __attribute__((ext_vector_type(4))) float f32x4;

__device__ __forceinline__ ushort f2bf(float f) {           // RNE f32->bf16
    unsigned u = __float_as_uint(f);
    return (ushort)((u + 0x7fffu + ((u >> 16) & 1u)) >> 16);
}
__device__ __forceinline__ float bf2f(ushort h) {
    return __uint_as_float((unsigned)h << 16);
}

__global__ void deg_kernel(const int* __restrict__ col, const float* __restrict__ ew,
                           float* __restrict__ deg, int* __restrict__ cnt, int E) {
    int e = blockIdx.x * blockDim.x + threadIdx.x;
    if (e < E) {
        int c = col[e];
        atomicAdd(&deg[c], ew[e]);
        atomicAdd(&cnt[c], 1);
    }
}

__global__ void dinv_kernel(float* deg, int N) {
    int n = blockIdx.x * blockDim.x + threadIdx.x;
    if (n < N) {
        float d = deg[n] + 1.0f;
        deg[n] = (d > 0.0f) ? rsqrtf(d) : 0.0f;
    }
}

// ---- 3-pass scan: cnt[N] -> exclusive rowptr[N+1] (+cursor copy) ----
__global__ __launch_bounds__(256) void scan_part_kernel(
        const int* __restrict__ cnt, int* __restrict__ partial, int N) {
    const int T = SCAN_BLOCKS * 256;
    const int chunk = (N + T - 1) / T;
    const int j = blockIdx.x * 256 + threadIdx.x;
    const int s = j * chunk, e = min(s + chunk, N);
    int acc = 0;
    for (int i = s; i < e; i++) acc += cnt[i];
    __shared__ int red[256];
    red[threadIdx.x] = acc;
    __syncthreads();
    for (int off = 128; off > 0; off >>= 1) {
        if (threadIdx.x < off) red[threadIdx.x] += red[threadIdx.x + off];
        __syncthreads();
    }
    if (threadIdx.x == 0) partial[blockIdx.x] = red[0];
}

__global__ __launch_bounds__(256) void scan_tops_kernel(int* __restrict__ partial) {
    __shared__ int sh[256];
    const int t = threadIdx.x;
    int v = (t < SCAN_BLOCKS) ? partial[t] : 0;
    sh[t] = v;
    __syncthreads();
    for (int off = 1; off < 256; off <<= 1) {
        int x = sh[t];
        int a = (t >= off) ? sh[t - off] : 0;
        __syncthreads();
        sh[t] = x + a;
        __syncthreads();
    }
    if (t < SCAN_BLOCKS) partial[t] = (t == 0) ? 0 : sh[t - 1];
}

__global__ __launch_bounds__(256) void scan_write_kernel(
        const int* __restrict__ cnt, const int* __restrict__ partial,
        int* __restrict__ rowptr, int* __restrict__ cursor, int N) {
    const int T = SCAN_BLOCKS * 256;
    const int chunk = (N + T - 1) / T;
    const int j = blockIdx.x * 256 + threadIdx.x;
    const int s = j * chunk, e = min(s + chunk, N);
    int acc = 0;
    for (int i = s; i < e; i++) acc += cnt[i];
    __shared__ int sh[256];
    const int t = threadIdx.x;
    sh[t] = acc;
    __syncthreads();
    for (int off = 1; off < 256; off <<= 1) {
        int x = sh[t];
        int a = (t >= off) ? sh[t - off] : 0;
        __syncthreads();
        sh[t] = x + a;
        __syncthreads();
    }
    int excl = partial[blockIdx.x] + ((t == 0) ? 0 : sh[t - 1]);
    for (int i = s; i < e; i++) {
        rowptr[i] = excl;
        cursor[i] = excl;
        excl += cnt[i];
    }
    if (j == T - 1) rowptr[N] = excl;
}

__global__ void fill_kernel(const int* __restrict__ row, const int* __restrict__ col,
        const float* __restrict__ ew, const float* __restrict__ dinv,
        int* __restrict__ cursor, int* __restrict__ csr_src, float* __restrict__ csr_w, int E) {
    int e = blockIdx.x * blockDim.x + threadIdx.x;
    if (e < E) {
        const int c = col[e], r = row[e];
        const int p = atomicAdd(&cursor[c], 1);
        csr_src[p] = r;
        csr_w[p] = ew[e] * dinv[r];
    }
}

// X f32 [N][128] -> bf16, 4 elems/thread
__global__ __launch_bounds__(256) void cvt_x_kernel(
        const float* __restrict__ X, ushort* __restrict__ Xb, int total4) {
    int i = blockIdx.x * 256 + threadIdx.x;
    if (i < total4) {
        float4 v = reinterpret_cast<const float4*>(X)[i];
        ushort4 o;
        o.x = f2bf(v.x); o.y = f2bf(v.y); o.z = f2bf(v.z); o.w = f2bf(v.w);
        reinterpret_cast<ushort4*>(Xb)[i] = o;
    }
}

// W f32 [128][DOUT] -> Wt bf16 [DOUT][128] (transposed so MFMA B-frag is
// contiguous along k)
template <int DOUT>
__global__ __launch_bounds__(256) void cvt_wt_kernel(
        const float* __restrict__ W, ushort* __restrict__ Wt) {
    int o = blockIdx.x * 256 + threadIdx.x;
    if (o < DOUT * 128) {
        int c = o >> 7, k = o & 127;
        Wt[o] = f2bf(W[(size_t)k * DOUT + c]);
    }
}

// MFMA GEMM: Y[N,DOUT] = Xb[N,128] @ Wt^T.  One-shot K=128, 128-row tile,
// whole DOUT width, 4 waves.  LDS XOR-swizzled (byte ^= (row&7)<<4) so
// frag ds_read_b128 hits the 8-cyc floor.
template <int DOUT, bool OUT_BF16>
__global__ __launch_bounds__(256, 2) void mfma_gemm_kernel(
        const ushort* __restrict__ Xb, const ushort* __restrict__ Wt,
        void* __restrict__ Y, int N) {
    constexpr int CW = DOUT / 64;     // col-waves: 2 (DOUT=128) or 1 (64)
    constexpr int RW = 4 / CW;        // row-waves: 2 or 4
    constexpr int WROWS = 128 / RW;   // rows per wave: 64 or 32
    constexpr int MI = WROWS / 16;    // row frags: 4 or 2
    __shared__ __align__(16) ushort sX[128 * 128];   // 32 KB
    __shared__ __align__(16) ushort sW[DOUT * 128];  // 32/16 KB
    const int tid = threadIdx.x;
    const int base = blockIdx.x * 128;

    // stage X tile: 128 rows x 256B, 16B chunks, swizzled
    #pragma unroll
    for (int p = 0; p < 8; p++) {
        const int ch = p * 256 + tid;
        const int r = ch >> 4, cpos = ch & 15;
        const int grow = base + r;
        uint4 v = make_uint4(0, 0, 0, 0);
        if (grow < N)
            v = *reinterpret_cast<const uint4*>(Xb + (size_t)grow * 128 + cpos * 8);
        const int b = (cpos * 16) ^ ((r & 7) << 4);
        *reinterpret_cast<uint4*>(reinterpret_cast<char*>(sX) + r * 256 + b) = v;
    }
    // stage Wt: DOUT rows x 256B
    for (int ch = tid; ch < DOUT * 16; ch += 256) {
        const int r = ch >> 4, cpos = ch & 15;
        uint4 v = *reinterpret_cast<const uint4*>(Wt + (size_t)r * 128 + cpos * 8);
        const int b = (cpos * 16) ^ ((r & 7) << 4);
        *reinterpret_cast<uint4*>(reinterpret_cast<char*>(sW) + r * 256 + b) = v;
    }
    __syncthreads();

    const int lane = tid & 63;
    const int wid = tid >> 6;
    const int wr = wid / CW;
    const int wc = wid % CW;
    const int lr = lane & 15;
    const int g  = lane >> 4;

    f32x4 acc[MI][4];
    #pragma unroll
    for (int i = 0; i < MI; i++)
        #pragma unroll
        for (int f = 0; f < 4; f++)
            acc[i][f] = (f32x4){0.f, 0.f, 0.f, 0.f};

    #pragma unroll
    for (int ks = 0; ks < 4; ks++) {
        const int koff = ks * 64 + g * 16;   // byte offset along k
        short8 a[MI], b[4];
        #pragma unroll
        for (int i = 0; i < MI; i++) {
            const int row = wr * WROWS + i * 16 + lr;
            a[i] = *reinterpret_cast<const short8*>(
                reinterpret_cast<const char*>(sX) + row * 256 + (koff ^ ((row & 7) << 4)));
        }
        #pragma unroll
        for (int f = 0; f < 4; f++) {
            const int col = wc * 64 + f * 16 + lr;
            b[f] = *reinterpret_cast<const short8*>(
                reinterpret_cast<const char*>(sW) + col * 256 + (koff ^ ((col & 7) << 4)));
        }
        #pragma unroll
        for (int i = 0; i < MI; i++)
            #pragma unroll
            for (int f = 0; f < 4; f++)
                acc[i][f] = __builtin_amdgcn_mfma_f32_16x16x32_bf16(a[i], b[f], acc[i][f], 0, 0, 0);
    }

    // epilogue: D row = (lane>>4)*4 + reg, col = lane&15  [m89-verified]
    #pragma unroll
    for (int i = 0; i < MI; i++) {
        #pragma unroll
        for (int reg = 0; reg < 4; reg++) {
            const int grow = base + wr * WROWS + i * 16 + g * 4 + reg;
            if (grow < N) {
                #pragma unroll
                for (int f = 0; f < 4; f++) {
                    const int gcol = wc * 64 + f * 16 + lr;
                    const float v = acc[i][f][reg];
                    if (OUT_BF16)
                        ((ushort*)Y)[(size_t)grow * DOUT + gcol] = f2bf(v);
                    else
                        ((float*)Y)[(size_t)grow * DOUT + gcol] = v;
                }
            }
        }
    }
}

// Layer-1 aggregation: bf16 src (xw), f32 accumulate, bf16 dst (h), fused
// self-loop + bias + relu.  32 lanes/node, 4 cols each (ushort4 = 8B).
__global__ __launch_bounds__(256) void agg1_kernel(
        const int* __restrict__ rowptr, const int* __restrict__ csr_src,
        const float* __restrict__ csr_w, const float* __restrict__ dinv,
        const ushort* __restrict__ src, const float* __restrict__ bias,
        ushort* __restrict__ dst, int N) {
    const long long gid = (long long)blockIdx.x * blockDim.x + threadIdx.x;
    const int c = (int)(gid >> 5);
    if (c >= N) return;
    const int lane = (int)(gid & 31);
    const float di = dinv[c];
    const float sl = di * di;
    ushort4 s4 = *reinterpret_cast<const ushort4*>(src + (size_t)c * 128 + lane * 4);
    float ax = bf2f(s4.x) * sl, ay = bf2f(s4.y) * sl,
          az = bf2f(s4.z) * sl, aw = bf2f(s4.w) * sl;
    const int e0 = rowptr[c], e1 = rowptr[c + 1];
    for (int e = e0; e < e1; e++) {
        const int s = csr_src[e];
        const float w = csr_w[e] * di;
        ushort4 v4 = *reinterpret_cast<const ushort4*>(src + (size_t)s * 128 + lane * 4);
        ax += bf2f(v4.x) * w; ay += bf2f(v4.y) * w;
        az += bf2f(v4.z) * w; aw += bf2f(v4.w) * w;
    }
    const float4 b = reinterpret_cast<const float4*>(bias)[lane];
    ax = fmaxf(ax + b.x, 0.f); ay = fmaxf(ay + b.y, 0.f);
    az = fmaxf(az + b.z, 0.f); aw = fmaxf(aw + b.w, 0.f);
    ushort4 o;
    o.x = f2bf(ax); o.y = f2bf(ay); o.z = f2bf(az); o.w = f2bf(aw);
    *reinterpret_cast<ushort4*>(dst + (size_t)c * 128 + lane * 4) = o;
}

// Layer-2 aggregation: f32 src (hw), f32 out, fused self-loop + bias.
__global__ __launch_bounds__(256) void agg2_kernel(
        const int* __restrict__ rowptr, const int* __restrict__ csr_src,
        const float* __restrict__ csr_w, const float* __restrict__ dinv,
        const float* __restrict__ src, const float* __restrict__ bias,
        float* __restrict__ dst, int N) {
    const long long gid = (long long)blockIdx.x * blockDim.x + threadIdx.x;
    const int c = (int)(gid >> 4);
    if (c >= N) return;
    const int lane = (int)(gid & 15);
    const float di = dinv[c];
    const float sl = di * di;
    float4 sv = reinterpret_cast<const float4*>(src)[(size_t)c * 16 + lane];
    float4 acc;
    acc.x = sv.x * sl; acc.y = sv.y * sl; acc.z = sv.z * sl; acc.w = sv.w * sl;
    const int e0 = rowptr[c], e1 = rowptr[c + 1];
    for (int e = e0; e < e1; e++) {
        const int s = csr_src[e];
        const float w = csr_w[e] * di;
        const float4 v = reinterpret_cast<const float4*>(src)[(size_t)s * 16 + lane];
        acc.x += v.x * w; acc.y += v.y * w;
        acc.z += v.z * w; acc.w += v.w * w;
    }
    const float4 b = reinterpret_cast<const float4*>(bias)[lane];
    acc.x += b.x; acc.y += b.y; acc.z += b.z; acc.w += b.w;
    reinterpret_cast<float4*>(dst)[(size_t)c * 16 + lane] = acc;
}

extern "C" void kernel_launch(void* const* d_in, const int* in_sizes, int n_in,
                              void* d_out, int out_size, void* d_ws, size_t ws_size,
                              hipStream_t stream) {
    const float* x  = (const float*)d_in[0];
    const int*   ei = (const int*)d_in[1];
    const float* ew = (const float*)d_in[2];
    const float* W1 = (const float*)d_in[3];
    const float* b1 = (const float*)d_in[4];
    const float* W2 = (const float*)d_in[5];
    const float* b2 = (const float*)d_in[6];
    const int N = in_sizes[0] / 128;
    const int E = in_sizes[1] / 2;
    const int* row = ei;
    const int* col = ei + E;

    // byte-based workspace layout (all offsets 16B-aligned for N%? N*4=400000 ok)
    char* w = (char*)d_ws;
    float* dinv = (float*)w;                 w += (size_t)N * 4;
    ushort* Xb  = (ushort*)w;                // bf16 X   [N][128]
    float*  A2  = (float*)w;                 // f32 hw   [N][64]  (aliases Xb; Xb dead by then)
                                             w += (size_t)N * 256;
    ushort* Ab  = (ushort*)w;                w += (size_t)N * 256;  // bf16 xw [N][128]
    ushort* Hb  = (ushort*)w;                w += (size_t)N * 256;  // bf16 h  [N][128]
    ushort* W1t = (ushort*)w;                w += 128 * 128 * 2;
    ushort* W2t = (ushort*)w;                w += 64 * 128 * 2;
    int* cnt    = (int*)w;                   w += (size_t)N * 4;
    int* rowptr = (int*)w;                   w += (size_t)(N + 1) * 4;
    int* cursor = (int*)w;                   w += (size_t)N * 4;
    int* partial= (int*)w;                   w += SCAN_BLOCKS * 4;
    int* csr_src= (int*)w;                   w += (size_t)E * 4;
    float* csr_w= (float*)w;
    float* out  = (float*)d_out;

    hipMemsetAsync(dinv, 0, (size_t)N * sizeof(float), stream);
    hipMemsetAsync(cnt,  0, (size_t)N * sizeof(int), stream);

    deg_kernel<<<(E + 255) / 256, 256, 0, stream>>>(col, ew, dinv, cnt, E);
    dinv_kernel<<<(N + 255) / 256, 256, 0, stream>>>(dinv, N);
    scan_part_kernel<<<SCAN_BLOCKS, 256, 0, stream>>>(cnt, partial, N);
    scan_tops_kernel<<<1, 256, 0, stream>>>(partial);
    scan_write_kernel<<<SCAN_BLOCKS, 256, 0, stream>>>(cnt, partial, rowptr, cursor, N);
    fill_kernel<<<(E + 255) / 256, 256, 0, stream>>>(row, col, ew, dinv, cursor,
                                                     csr_src, csr_w, E);

    cvt_x_kernel<<<(N * 32 + 255) / 256, 256, 0, stream>>>(x, Xb, N * 32);
    cvt_wt_kernel<128><<<(128 * 128 + 255) / 256, 256, 0, stream>>>(W1, W1t);
    cvt_wt_kernel<64><<<(64 * 128 + 255) / 256, 256, 0, stream>>>(W2, W2t);

    const int ntiles = (N + 127) / 128;

    // ---- layer 1: Hb = relu(Ahat @ (X W1) + b1)   (bf16 xw, bf16 h)
    mfma_gemm_kernel<128, true><<<ntiles, 256, 0, stream>>>(Xb, W1t, Ab, N);
    agg1_kernel<<<(int)(((long long)N * 32 + 255) / 256), 256, 0, stream>>>(
        rowptr, csr_src, csr_w, dinv, Ab, b1, Hb, N);

    // ---- layer 2: out = Ahat @ (Hb W2) + b2      (f32 hw, f32 out)
    mfma_gemm_kernel<64, false><<<ntiles, 256, 0, stream>>>(Hb, W2t, A2, N);
    agg2_kernel<<<(int)(((long long)N * 16 + 255) / 256), 256, 0, stream>>>(
        rowptr, csr_src, csr_w, dinv, A2, b2, out, N);
}

// Round 6
// 216.672 us; speedup vs baseline: 7.9605x; 1.1228x over previous
//
#include <hip/hip_runtime.h>

// 2-layer GCN: atomic-light CSR build + bf16 MFMA GEMMs + gather aggregation.
// Pipeline: cnt histogram -> scan -> fill(raw ew) -> CSR degree sum -> dinv
// -> premult csr_w by dinv[src] -> [cvt to bf16] -> gemm1/agg1 -> gemm2/agg2.

constexpr int SCAN_BLOCKS = 256;

typedef __attribute__((ext_vector_type(8))) short short8;   // 8 bf16 (4 VGPR)
typedef __attribute__((ext_vector_type(4))) float f32x4;

__device__ __forceinline__ ushort f2bf(float f) {           // RNE f32->bf16
    unsigned u = __float_as_uint(f);
    return (ushort)((u + 0x7fffu + ((u >> 16) & 1u)) >> 16);
}
__device__ __forceinline__ float bf2f(ushort h) {
    return __uint_as_float((unsigned)h << 16);
}

// int histogram of col[]; 4 edges/thread (independent atomic chains)
__global__ void cnt_kernel(const int* __restrict__ col, int* __restrict__ cnt, int E) {
    const int stride = gridDim.x * blockDim.x;
    for (int e = blockIdx.x * blockDim.x + threadIdx.x; e < E; e += stride)
        atomicAdd(&cnt[col[e]], 1);
}

// ---- 3-pass scan: cnt[N] -> exclusive rowptr[N+1] (+cursor copy) ----
__global__ __launch_bounds__(256) void scan_part_kernel(
        const int* __restrict__ cnt, int* __restrict__ partial, int N) {
    const int T = SCAN_BLOCKS * 256;
    const int chunk = (N + T - 1) / T;
    const int j = blockIdx.x * 256 + threadIdx.x;
    const int s = j * chunk, e = min(s + chunk, N);
    int acc = 0;
    for (int i = s; i < e; i++) acc += cnt[i];
    __shared__ int red[256];
    red[threadIdx.x] = acc;
    __syncthreads();
    for (int off = 128; off > 0; off >>= 1) {
        if (threadIdx.x < off) red[threadIdx.x] += red[threadIdx.x + off];
        __syncthreads();
    }
    if (threadIdx.x == 0) partial[blockIdx.x] = red[0];
}

__global__ __launch_bounds__(256) void scan_tops_kernel(int* __restrict__ partial) {
    __shared__ int sh[256];
    const int t = threadIdx.x;
    int v = (t < SCAN_BLOCKS) ? partial[t] : 0;
    sh[t] = v;
    __syncthreads();
    for (int off = 1; off < 256; off <<= 1) {
        int x = sh[t];
        int a = (t >= off) ? sh[t - off] : 0;
        __syncthreads();
        sh[t] = x + a;
        __syncthreads();
    }
    if (t < SCAN_BLOCKS) partial[t] = (t == 0) ? 0 : sh[t - 1];
}

__global__ __launch_bounds__(256) void scan_write_kernel(
        const int* __restrict__ cnt, const int* __restrict__ partial,
        int* __restrict__ rowptr, int* __restrict__ cursor, int N) {
    const int T = SCAN_BLOCKS * 256;
    const int chunk = (N + T - 1) / T;
    const int j = blockIdx.x * 256 + threadIdx.x;
    const int s = j * chunk, e = min(s + chunk, N);
    int acc = 0;
    for (int i = s; i < e; i++) acc += cnt[i];
    __shared__ int sh[256];
    const int t = threadIdx.x;
    sh[t] = acc;
    __syncthreads();
    for (int off = 1; off < 256; off <<= 1) {
        int x = sh[t];
        int a = (t >= off) ? sh[t - off] : 0;
        __syncthreads();
        sh[t] = x + a;
        __syncthreads();
    }
    int excl = partial[blockIdx.x] + ((t == 0) ? 0 : sh[t - 1]);
    for (int i = s; i < e; i++) {
        rowptr[i] = excl;
        cursor[i] = excl;
        excl += cnt[i];
    }
    if (j == T - 1) rowptr[N] = excl;
}

// fill CSR with {src, raw ew} interleaved (one 8B store per edge)
__global__ void fill_kernel(const int* __restrict__ row, const int* __restrict__ col,
        const float* __restrict__ ew, int* __restrict__ cursor,
        int2* __restrict__ csr, int E) {
    const int stride = gridDim.x * blockDim.x;
    for (int e = blockIdx.x * blockDim.x + threadIdx.x; e < E; e += stride) {
        const int c = col[e], r = row[e];
        const int p = atomicAdd(&cursor[c], 1);
        csr[p] = make_int2(r, __float_as_int(ew[e]));
    }
}

// per-node degree from CSR range (no atomics): dinv[n] = rsqrt(1 + sum ew)
__global__ __launch_bounds__(256) void degsum_kernel(
        const int* __restrict__ rowptr, const int2* __restrict__ csr,
        float* __restrict__ dinv, int N) {
    const int n = blockIdx.x * blockDim.x + threadIdx.x;
    if (n >= N) return;
    const int e0 = rowptr[n], e1 = rowptr[n + 1];
    float d = 1.0f;                       // self loop
    for (int e = e0; e < e1; e++) d += __int_as_float(csr[e].y);
    dinv[n] = (d > 0.0f) ? rsqrtf(d) : 0.0f;
}

// csr.w *= dinv[src]
__global__ void premult_kernel(int2* __restrict__ csr, const float* __restrict__ dinv, int E) {
    const int e = blockIdx.x * blockDim.x + threadIdx.x;
    if (e < E) {
        int2 c = csr[e];
        ((float*)csr)[2 * (size_t)e + 1] = __int_as_float(c.y) * dinv[c.x];
    }
}

// X f32 [N][128] -> bf16, 4 elems/thread
__global__ __launch_bounds__(256) void cvt_x_kernel(
        const float* __restrict__ X, ushort* __restrict__ Xb, int total4) {
    int i = blockIdx.x * 256 + threadIdx.x;
    if (i < total4) {
        float4 v = reinterpret_cast<const float4*>(X)[i];
        ushort4 o;
        o.x = f2bf(v.x); o.y = f2bf(v.y); o.z = f2bf(v.z); o.w = f2bf(v.w);
        reinterpret_cast<ushort4*>(Xb)[i] = o;
    }
}

// W f32 [128][DOUT] -> Wt bf16 [DOUT][128] (transposed: B-frag contiguous in k)
template <int DOUT>
__global__ __launch_bounds__(256) void cvt_wt_kernel(
        const float* __restrict__ W, ushort* __restrict__ Wt) {
    int o = blockIdx.x * 256 + threadIdx.x;
    if (o < DOUT * 128) {
        int c = o >> 7, k = o & 127;
        Wt[o] = f2bf(W[(size_t)k * DOUT + c]);
    }
}

// MFMA GEMM: Y[N,DOUT] = Xb[N,128] @ Wt^T.  One-shot K=128, 128-row tile,
// 4 waves, XOR-swizzled LDS (byte ^= (row&7)<<4).
template <int DOUT, bool OUT_BF16>
__global__ __launch_bounds__(256, 2) void mfma_gemm_kernel(
        const ushort* __restrict__ Xb, const ushort* __restrict__ Wt,
        void* __restrict__ Y, int N) {
    constexpr int CW = DOUT / 64;     // col-waves
    constexpr int RW = 4 / CW;        // row-waves
    constexpr int WROWS = 128 / RW;
    constexpr int MI = WROWS / 16;
    __shared__ __align__(16) ushort sX[128 * 128];
    __shared__ __align__(16) ushort sW[DOUT * 128];
    const int tid = threadIdx.x;
    const int base = blockIdx.x * 128;

    #pragma unroll
    for (int p = 0; p < 8; p++) {
        const int ch = p * 256 + tid;
        const int r = ch >> 4, cpos = ch & 15;
        const int grow = base + r;
        uint4 v = make_uint4(0, 0, 0, 0);
        if (grow < N)
            v = *reinterpret_cast<const uint4*>(Xb + (size_t)grow * 128 + cpos * 8);
        const int b = (cpos * 16) ^ ((r & 7) << 4);
        *reinterpret_cast<uint4*>(reinterpret_cast<char*>(sX) + r * 256 + b) = v;
    }
    for (int ch = tid; ch < DOUT * 16; ch += 256) {
        const int r = ch >> 4, cpos = ch & 15;
        uint4 v = *reinterpret_cast<const uint4*>(Wt + (size_t)r * 128 + cpos * 8);
        const int b = (cpos * 16) ^ ((r & 7) << 4);
        *reinterpret_cast<uint4*>(reinterpret_cast<char*>(sW) + r * 256 + b) = v;
    }
    __syncthreads();

    const int lane = tid & 63;
    const int wid = tid >> 6;
    const int wr = wid / CW;
    const int wc = wid % CW;
    const int lr = lane & 15;
    const int g  = lane >> 4;

    f32x4 acc[MI][4];
    #pragma unroll
    for (int i = 0; i < MI; i++)
        #pragma unroll
        for (int f = 0; f < 4; f++)
            acc[i][f] = (f32x4){0.f, 0.f, 0.f, 0.f};

    #pragma unroll
    for (int ks = 0; ks < 4; ks++) {
        const int koff = ks * 64 + g * 16;
        short8 a[MI], b[4];
        #pragma unroll
        for (int i = 0; i < MI; i++) {
            const int row = wr * WROWS + i * 16 + lr;
            a[i] = *reinterpret_cast<const short8*>(
                reinterpret_cast<const char*>(sX) + row * 256 + (koff ^ ((row & 7) << 4)));
        }
        #pragma unroll
        for (int f = 0; f < 4; f++) {
            const int col = wc * 64 + f * 16 + lr;
            b[f] = *reinterpret_cast<const short8*>(
                reinterpret_cast<const char*>(sW) + col * 256 + (koff ^ ((col & 7) << 4)));
        }
        #pragma unroll
        for (int i = 0; i < MI; i++)
            #pragma unroll
            for (int f = 0; f < 4; f++)
                acc[i][f] = __builtin_amdgcn_mfma_f32_16x16x32_bf16(a[i], b[f], acc[i][f], 0, 0, 0);
    }

    #pragma unroll
    for (int i = 0; i < MI; i++) {
        #pragma unroll
        for (int reg = 0; reg < 4; reg++) {
            const int grow = base + wr * WROWS + i * 16 + g * 4 + reg;
            if (grow < N) {
                #pragma unroll
                for (int f = 0; f < 4; f++) {
                    const int gcol = wc * 64 + f * 16 + lr;
                    const float v = acc[i][f][reg];
                    if (OUT_BF16)
                        ((ushort*)Y)[(size_t)grow * DOUT + gcol] = f2bf(v);
                    else
                        ((float*)Y)[(size_t)grow * DOUT + gcol] = v;
                }
            }
        }
    }
}

// Layer-1 aggregation: bf16 src, f32 accum, bf16 dst; self-loop+bias+relu.
__global__ __launch_bounds__(256) void agg1_kernel(
        const int* __restrict__ rowptr, const int2* __restrict__ csr,
        const float* __restrict__ dinv,
        const ushort* __restrict__ src, const float* __restrict__ bias,
        ushort* __restrict__ dst, int N) {
    const long long gid = (long long)blockIdx.x * blockDim.x + threadIdx.x;
    const int c = (int)(gid >> 5);
    if (c >= N) return;
    const int lane = (int)(gid & 31);
    const float di = dinv[c];
    const float sl = di * di;
    ushort4 s4 = *reinterpret_cast<const ushort4*>(src + (size_t)c * 128 + lane * 4);
    float ax = bf2f(s4.x) * sl, ay = bf2f(s4.y) * sl,
          az = bf2f(s4.z) * sl, aw = bf2f(s4.w) * sl;
    const int e0 = rowptr[c], e1 = rowptr[c + 1];
    for (int e = e0; e < e1; e++) {
        const int2 ce = csr[e];
        const float w = __int_as_float(ce.y) * di;
        ushort4 v4 = *reinterpret_cast<const ushort4*>(src + (size_t)ce.x * 128 + lane * 4);
        ax += bf2f(v4.x) * w; ay += bf2f(v4.y) * w;
        az += bf2f(v4.z) * w; aw += bf2f(v4.w) * w;
    }
    const float4 b = reinterpret_cast<const float4*>(bias)[lane];
    ax = fmaxf(ax + b.x, 0.f); ay = fmaxf(ay + b.y, 0.f);
    az = fmaxf(az + b.z, 0.f); aw = fmaxf(aw + b.w, 0.f);
    ushort4 o;
    o.x = f2bf(ax); o.y = f2bf(ay); o.z = f2bf(az); o.w = f2bf(aw);
    *reinterpret_cast<ushort4*>(dst + (size_t)c * 128 + lane * 4) = o;
}

// Layer-2 aggregation: bf16 src (hw), f32 accum, f32 out; self-loop+bias.
__global__ __launch_bounds__(256) void agg2_kernel(
        const int* __restrict__ rowptr, const int2* __restrict__ csr,
        const float* __restrict__ dinv,
        const ushort* __restrict__ src, const float* __restrict__ bias,
        float* __restrict__ dst, int N) {
    const long long gid = (long long)blockIdx.x * blockDim.x + threadIdx.x;
    const int c = (int)(gid >> 4);
    if (c >= N) return;
    const int lane = (int)(gid & 15);
    const float di = dinv[c];
    const float sl = di * di;
    ushort4 s4 = *reinterpret_cast<const ushort4*>(src + (size_t)c * 64 + lane * 4);
    float ax = bf2f(s4.x) * sl, ay = bf2f(s4.y) * sl,
          az = bf2f(s4.z) * sl, aw = bf2f(s4.w) * sl;
    const int e0 = rowptr[c], e1 = rowptr[c + 1];
    for (int e = e0; e < e1; e++) {
        const int2 ce = csr[e];
        const float w = __int_as_float(ce.y) * di;
        ushort4 v4 = *reinterpret_cast<const ushort4*>(src + (size_t)ce.x * 64 + lane * 4);
        ax += bf2f(v4.x) * w; ay += bf2f(v4.y) * w;
        az += bf2f(v4.z) * w; aw += bf2f(v4.w) * w;
    }
    const float4 b = reinterpret_cast<const float4*>(bias)[lane];
    float4 o = make_float4(ax + b.x, ay + b.y, az + b.z, aw + b.w);
    reinterpret_cast<float4*>(dst)[(size_t)c * 16 + lane] = o;
}

extern "C" void kernel_launch(void* const* d_in, const int* in_sizes, int n_in,
                              void* d_out, int out_size, void* d_ws, size_t ws_size,
                              hipStream_t stream) {
    const float* x  = (const float*)d_in[0];
    const int*   ei = (const int*)d_in[1];
    const float* ew = (const float*)d_in[2];
    const float* W1 = (const float*)d_in[3];
    const float* b1 = (const float*)d_in[4];
    const float* W2 = (const float*)d_in[5];
    const float* b2 = (const float*)d_in[6];
    const int N = in_sizes[0] / 128;
    const int E = in_sizes[1] / 2;
    const int* row = ei;
    const int* col = ei + E;

    char* w = (char*)d_ws;
    float* dinv = (float*)w;                 w += (size_t)N * 4;
    ushort* Xb  = (ushort*)w;                // bf16 X [N][128]; dead after gemm1
    ushort* Gb  = (ushort*)w;                // bf16 hw [N][64] (aliases Xb)
                                             w += (size_t)N * 256;
    ushort* Ab  = (ushort*)w;                w += (size_t)N * 256;  // bf16 xw
    ushort* Hb  = (ushort*)w;                w += (size_t)N * 256;  // bf16 h
    ushort* W1t = (ushort*)w;                w += 128 * 128 * 2;
    ushort* W2t = (ushort*)w;                w += 64 * 128 * 2;
    int* cnt    = (int*)w;                   w += (size_t)N * 4;
    int* rowptr = (int*)w;                   w += (size_t)(N + 1) * 4;
    int* cursor = (int*)w;                   w += (size_t)N * 4;
    int* partial= (int*)w;                   w += SCAN_BLOCKS * 4;
    int2* csr   = (int2*)w;
    float* out  = (float*)d_out;

    hipMemsetAsync(cnt, 0, (size_t)N * sizeof(int), stream);

    const int eb4 = (E / 4 + 255) / 256;     // 4 edges/thread
    cnt_kernel<<<eb4, 256, 0, stream>>>(col, cnt, E);
    scan_part_kernel<<<SCAN_BLOCKS, 256, 0, stream>>>(cnt, partial, N);
    scan_tops_kernel<<<1, 256, 0, stream>>>(partial);
    scan_write_kernel<<<SCAN_BLOCKS, 256, 0, stream>>>(cnt, partial, rowptr, cursor, N);
    fill_kernel<<<eb4, 256, 0, stream>>>(row, col, ew, cursor, csr, E);
    degsum_kernel<<<(N + 255) / 256, 256, 0, stream>>>(rowptr, csr, dinv, N);
    premult_kernel<<<(E + 255) / 256, 256, 0, stream>>>(csr, dinv, E);

    cvt_x_kernel<<<(N * 32 + 255) / 256, 256, 0, stream>>>(x, Xb, N * 32);
    cvt_wt_kernel<128><<<(128 * 128 + 255) / 256, 256, 0, stream>>>(W1, W1t);
    cvt_wt_kernel<64><<<(64 * 128 + 255) / 256, 256, 0, stream>>>(W2, W2t);

    const int ntiles = (N + 127) / 128;

    // ---- layer 1: Hb = relu(Ahat @ (X W1) + b1)
    mfma_gemm_kernel<128, true><<<ntiles, 256, 0, stream>>>(Xb, W1t, Ab, N);
    agg1_kernel<<<(int)(((long long)N * 32 + 255) / 256), 256, 0, stream>>>(
        rowptr, csr, dinv, Ab, b1, Hb, N);

    // ---- layer 2: out = Ahat @ (Hb W2) + b2
    mfma_gemm_kernel<64, true><<<ntiles, 256, 0, stream>>>(Hb, W2t, Gb, N);
    agg2_kernel<<<(int)(((long long)N * 16 + 255) / 256), 256, 0, stream>>>(
        rowptr, csr, dinv, Gb, b2, out, N);
}

// Round 7
// 161.319 us; speedup vs baseline: 10.6920x; 1.3431x over previous
//
#include <hip/hip_runtime.h>

// 2-layer GCN: atomic-light CSR build + bf16 MFMA GEMMs + MLP-unrolled
// gather aggregation.
// Pipeline: cnt(+rank) -> scan -> fill(plain store) -> degsum/dinv ->
// misc(premult + bf16 converts) -> gemm1 -> agg1 -> gemm2 -> agg2.

constexpr int SCAN_BLOCKS = 256;

typedef __attribute__((ext_vector_type(8))) short short8;   // 8 bf16 (4 VGPR)
typedef __attribute__((ext_vector_type(4))) float f32x4;

__device__ __forceinline__ ushort f2bf(float f) {           // RNE f32->bf16
    unsigned u = __float_as_uint(f);
    return (ushort)((u + 0x7fffu + ((u >> 16) & 1u)) >> 16);
}
__device__ __forceinline__ float bf2f(ushort h) {
    return __uint_as_float((unsigned)h << 16);
}

// histogram of col[] + per-edge rank within its destination bucket
__global__ void cnt_kernel(const int* __restrict__ col, int* __restrict__ cnt,
                           int* __restrict__ rank, int E) {
    const int stride = gridDim.x * blockDim.x;
    for (int e = blockIdx.x * blockDim.x + threadIdx.x; e < E; e += stride)
        rank[e] = atomicAdd(&cnt[col[e]], 1);
}

// ---- 3-pass scan: cnt[N] -> exclusive rowptr[N+1] ----
__global__ __launch_bounds__(256) void scan_part_kernel(
        const int* __restrict__ cnt, int* __restrict__ partial, int N) {
    const int T = SCAN_BLOCKS * 256;
    const int chunk = (N + T - 1) / T;
    const int j = blockIdx.x * 256 + threadIdx.x;
    const int s = j * chunk, e = min(s + chunk, N);
    int acc = 0;
    for (int i = s; i < e; i++) acc += cnt[i];
    __shared__ int red[256];
    red[threadIdx.x] = acc;
    __syncthreads();
    for (int off = 128; off > 0; off >>= 1) {
        if (threadIdx.x < off) red[threadIdx.x] += red[threadIdx.x + off];
        __syncthreads();
    }
    if (threadIdx.x == 0) partial[blockIdx.x] = red[0];
}

__global__ __launch_bounds__(256) void scan_tops_kernel(int* __restrict__ partial) {
    __shared__ int sh[256];
    const int t = threadIdx.x;
    int v = (t < SCAN_BLOCKS) ? partial[t] : 0;
    sh[t] = v;
    __syncthreads();
    for (int off = 1; off < 256; off <<= 1) {
        int x = sh[t];
        int a = (t >= off) ? sh[t - off] : 0;
        __syncthreads();
        sh[t] = x + a;
        __syncthreads();
    }
    if (t < SCAN_BLOCKS) partial[t] = (t == 0) ? 0 : sh[t - 1];
}

__global__ __launch_bounds__(256) void scan_write_kernel(
        const int* __restrict__ cnt, const int* __restrict__ partial,
        int* __restrict__ rowptr, int N) {
    const int T = SCAN_BLOCKS * 256;
    const int chunk = (N + T - 1) / T;
    const int j = blockIdx.x * 256 + threadIdx.x;
    const int s = j * chunk, e = min(s + chunk, N);
    int acc = 0;
    for (int i = s; i < e; i++) acc += cnt[i];
    __shared__ int sh[256];
    const int t = threadIdx.x;
    sh[t] = acc;
    __syncthreads();
    for (int off = 1; off < 256; off <<= 1) {
        int x = sh[t];
        int a = (t >= off) ? sh[t - off] : 0;
        __syncthreads();
        sh[t] = x + a;
        __syncthreads();
    }
    int excl = partial[blockIdx.x] + ((t == 0) ? 0 : sh[t - 1]);
    for (int i = s; i < e; i++) {
        rowptr[i] = excl;
        excl += cnt[i];
    }
    if (j == T - 1) rowptr[N] = excl;
}

// fill CSR with {src, raw ew}; position from rowptr+rank (no atomics)
__global__ void fill_kernel(const int* __restrict__ row, const int* __restrict__ col,
        const float* __restrict__ ew, const int* __restrict__ rowptr,
        const int* __restrict__ rank, int2* __restrict__ csr, int E) {
    int e = blockIdx.x * blockDim.x + threadIdx.x;
    if (e < E) {
        const int p = rowptr[col[e]] + rank[e];
        csr[p] = make_int2(row[e], __float_as_int(ew[e]));
    }
}

// per-node degree from CSR range: dinv[n] = rsqrt(1 + sum ew)
__global__ __launch_bounds__(256) void degsum_kernel(
        const int* __restrict__ rowptr, const int2* __restrict__ csr,
        float* __restrict__ dinv, int N) {
    const int n = blockIdx.x * blockDim.x + threadIdx.x;
    if (n >= N) return;
    const int e0 = rowptr[n], e1 = rowptr[n + 1];
    float d = 1.0f;
    for (int e = e0; e < e1; e++) d += __int_as_float(csr[e].y);
    dinv[n] = (d > 0.0f) ? rsqrtf(d) : 0.0f;
}

// fused: premult csr.w *= dinv[src]  |  X->bf16  |  W1->W1t bf16  |  W2->W2t
__global__ __launch_bounds__(256) void misc_kernel(
        int2* __restrict__ csr, const float* __restrict__ dinv, int E,
        const float* __restrict__ X, ushort* __restrict__ Xb, int nx4,
        const float* __restrict__ W1, ushort* __restrict__ W1t,
        const float* __restrict__ W2, ushort* __restrict__ W2t) {
    const int nb_x = (nx4 + 255) / 256;
    const int nb_p = (E + 255) / 256;
    int b = blockIdx.x;
    if (b < nb_x) {                        // cvt X
        const int i = b * 256 + threadIdx.x;
        if (i < nx4) {
            float4 v = reinterpret_cast<const float4*>(X)[i];
            ushort4 o;
            o.x = f2bf(v.x); o.y = f2bf(v.y); o.z = f2bf(v.z); o.w = f2bf(v.w);
            reinterpret_cast<ushort4*>(Xb)[i] = o;
        }
        return;
    }
    b -= nb_x;
    if (b < nb_p) {                        // premult
        const int e = b * 256 + threadIdx.x;
        if (e < E) {
            int2 c = csr[e];
            ((float*)csr)[2 * (size_t)e + 1] = __int_as_float(c.y) * dinv[c.x];
        }
        return;
    }
    b -= nb_p;
    if (b < 64) {                          // W1t[c*128+k] = W1[k*128+c]
        const int o = b * 256 + threadIdx.x;
        W1t[o] = f2bf(W1[(size_t)(o & 127) * 128 + (o >> 7)]);
        return;
    }
    b -= 64;
    {                                      // W2t[c*128+k] = W2[k*64+c]
        const int o = b * 256 + threadIdx.x;
        if (o < 64 * 128)
            W2t[o] = f2bf(W2[(size_t)(o & 127) * 64 + (o >> 7)]);
    }
}

// MFMA GEMM: Y[N,DOUT] = Xb[N,128] @ Wt^T.  K=128 one-shot, 128-row tile,
// 4 waves, XOR-swizzled LDS (byte ^= (row&7)<<4).
template <int DOUT, bool OUT_BF16>
__global__ __launch_bounds__(256, 2) void mfma_gemm_kernel(
        const ushort* __restrict__ Xb, const ushort* __restrict__ Wt,
        void* __restrict__ Y, int N) {
    constexpr int CW = DOUT / 64;
    constexpr int RW = 4 / CW;
    constexpr int WROWS = 128 / RW;
    constexpr int MI = WROWS / 16;
    __shared__ __align__(16) ushort sX[128 * 128];
    __shared__ __align__(16) ushort sW[DOUT * 128];
    const int tid = threadIdx.x;
    const int base = blockIdx.x * 128;

    #pragma unroll
    for (int p = 0; p < 8; p++) {
        const int ch = p * 256 + tid;
        const int r = ch >> 4, cpos = ch & 15;
        const int grow = base + r;
        uint4 v = make_uint4(0, 0, 0, 0);
        if (grow < N)
            v = *reinterpret_cast<const uint4*>(Xb + (size_t)grow * 128 + cpos * 8);
        const int b = (cpos * 16) ^ ((r & 7) << 4);
        *reinterpret_cast<uint4*>(reinterpret_cast<char*>(sX) + r * 256 + b) = v;
    }
    for (int ch = tid; ch < DOUT * 16; ch += 256) {
        const int r = ch >> 4, cpos = ch & 15;
        uint4 v = *reinterpret_cast<const uint4*>(Wt + (size_t)r * 128 + cpos * 8);
        const int b = (cpos * 16) ^ ((r & 7) << 4);
        *reinterpret_cast<uint4*>(reinterpret_cast<char*>(sW) + r * 256 + b) = v;
    }
    __syncthreads();

    const int lane = tid & 63;
    const int wid = tid >> 6;
    const int wr = wid / CW;
    const int wc = wid % CW;
    const int lr = lane & 15;
    const int g  = lane >> 4;

    f32x4 acc[MI][4];
    #pragma unroll
    for (int i = 0; i < MI; i++)
        #pragma unroll
        for (int f = 0; f < 4; f++)
            acc[i][f] = (f32x4){0.f, 0.f, 0.f, 0.f};

    #pragma unroll
    for (int ks = 0; ks < 4; ks++) {
        const int koff = ks * 64 + g * 16;
        short8 a[MI], b[4];
        #pragma unroll
        for (int i = 0; i < MI; i++) {
            const int row = wr * WROWS + i * 16 + lr;
            a[i] = *reinterpret_cast<const short8*>(
                reinterpret_cast<const char*>(sX) + row * 256 + (koff ^ ((row & 7) << 4)));
        }
        #pragma unroll
        for (int f = 0; f < 4; f++) {
            const int col = wc * 64 + f * 16 + lr;
            b[f] = *reinterpret_cast<const short8*>(
                reinterpret_cast<const char*>(sW) + col * 256 + (koff ^ ((col & 7) << 4)));
        }
        #pragma unroll
        for (int i = 0; i < MI; i++)
            #pragma unroll
            for (int f = 0; f < 4; f++)
                acc[i][f] = __builtin_amdgcn_mfma_f32_16x16x32_bf16(a[i], b[f], acc[i][f], 0, 0, 0);
    }

    #pragma unroll
    for (int i = 0; i < MI; i++) {
        #pragma unroll
        for (int reg = 0; reg < 4; reg++) {
            const int grow = base + wr * WROWS + i * 16 + g * 4 + reg;
            if (grow < N) {
                #pragma unroll
                for (int f = 0; f < 4; f++) {
                    const int gcol = wc * 64 + f * 16 + lr;
                    const float v = acc[i][f][reg];
                    if (OUT_BF16)
                        ((ushort*)Y)[(size_t)grow * DOUT + gcol] = f2bf(v);
                    else
                        ((float*)Y)[(size_t)grow * DOUT + gcol] = v;
                }
            }
        }
    }
}

// Layer-1 aggregation: bf16 src, f32 accum, bf16 dst; self-loop+bias+relu.
// 32 lanes/node; 4-wide unrolled edge loop (4 gathers in flight).
__global__ __launch_bounds__(256) void agg1_kernel(
        const int* __restrict__ rowptr, const int2* __restrict__ csr,
        const float* __restrict__ dinv,
        const ushort* __restrict__ src, const float* __restrict__ bias,
        ushort* __restrict__ dst, int N) {
    const long long gid = (long long)blockIdx.x * blockDim.x + threadIdx.x;
    const int c = (int)(gid >> 5);
    if (c >= N) return;
    const int lane = (int)(gid & 31);
    const float di = dinv[c];
    const float sl = di * di;
    ushort4 s4 = *reinterpret_cast<const ushort4*>(src + (size_t)c * 128 + lane * 4);
    float ax = bf2f(s4.x) * sl, ay = bf2f(s4.y) * sl,
          az = bf2f(s4.z) * sl, aw = bf2f(s4.w) * sl;
    const int e0 = rowptr[c], e1 = rowptr[c + 1];
    int e = e0;
    for (; e + 4 <= e1; e += 4) {
        const int2 c0 = csr[e], c1 = csr[e + 1], c2 = csr[e + 2], c3 = csr[e + 3];
        const ushort4 v0 = *reinterpret_cast<const ushort4*>(src + (size_t)c0.x * 128 + lane * 4);
        const ushort4 v1 = *reinterpret_cast<const ushort4*>(src + (size_t)c1.x * 128 + lane * 4);
        const ushort4 v2 = *reinterpret_cast<const ushort4*>(src + (size_t)c2.x * 128 + lane * 4);
        const ushort4 v3 = *reinterpret_cast<const ushort4*>(src + (size_t)c3.x * 128 + lane * 4);
        const float w0 = __int_as_float(c0.y) * di;
        const float w1 = __int_as_float(c1.y) * di;
        const float w2 = __int_as_float(c2.y) * di;
        const float w3 = __int_as_float(c3.y) * di;
        ax += bf2f(v0.x) * w0 + bf2f(v1.x) * w1 + bf2f(v2.x) * w2 + bf2f(v3.x) * w3;
        ay += bf2f(v0.y) * w0 + bf2f(v1.y) * w1 + bf2f(v2.y) * w2 + bf2f(v3.y) * w3;
        az += bf2f(v0.z) * w0 + bf2f(v1.z) * w1 + bf2f(v2.z) * w2 + bf2f(v3.z) * w3;
        aw += bf2f(v0.w) * w0 + bf2f(v1.w) * w1 + bf2f(v2.w) * w2 + bf2f(v3.w) * w3;
    }
    for (; e < e1; e++) {
        const int2 ce = csr[e];
        const float w = __int_as_float(ce.y) * di;
        const ushort4 v4 = *reinterpret_cast<const ushort4*>(src + (size_t)ce.x * 128 + lane * 4);
        ax += bf2f(v4.x) * w; ay += bf2f(v4.y) * w;
        az += bf2f(v4.z) * w; aw += bf2f(v4.w) * w;
    }
    const float4 b = reinterpret_cast<const float4*>(bias)[lane];
    ax = fmaxf(ax + b.x, 0.f); ay = fmaxf(ay + b.y, 0.f);
    az = fmaxf(az + b.z, 0.f); aw = fmaxf(aw + b.w, 0.f);
    ushort4 o;
    o.x = f2bf(ax); o.y = f2bf(ay); o.z = f2bf(az); o.w = f2bf(aw);
    *reinterpret_cast<ushort4*>(dst + (size_t)c * 128 + lane * 4) = o;
}

// Layer-2 aggregation: bf16 src (hw), f32 accum, f32 out; 16 lanes/node.
__global__ __launch_bounds__(256) void agg2_kernel(
        const int* __restrict__ rowptr, const int2* __restrict__ csr,
        const float* __restrict__ dinv,
        const ushort* __restrict__ src, const float* __restrict__ bias,
        float* __restrict__ dst, int N) {
    const long long gid = (long long)blockIdx.x * blockDim.x + threadIdx.x;
    const int c = (int)(gid >> 4);
    if (c >= N) return;
    const int lane = (int)(gid & 15);
    const float di = dinv[c];
    const float sl = di * di;
    ushort4 s4 = *reinterpret_cast<const ushort4*>(src + (size_t)c * 64 + lane * 4);
    float ax = bf2f(s4.x) * sl, ay = bf2f(s4.y) * sl,
          az = bf2f(s4.z) * sl, aw = bf2f(s4.w) * sl;
    const int e0 = rowptr[c], e1 = rowptr[c + 1];
    int e = e0;
    for (; e + 4 <= e1; e += 4) {
        const int2 c0 = csr[e], c1 = csr[e + 1], c2 = csr[e + 2], c3 = csr[e + 3];
        const ushort4 v0 = *reinterpret_cast<const ushort4*>(src + (size_t)c0.x * 64 + lane * 4);
        const ushort4 v1 = *reinterpret_cast<const ushort4*>(src + (size_t)c1.x * 64 + lane * 4);
        const ushort4 v2 = *reinterpret_cast<const ushort4*>(src + (size_t)c2.x * 64 + lane * 4);
        const ushort4 v3 = *reinterpret_cast<const ushort4*>(src + (size_t)c3.x * 64 + lane * 4);
        const float w0 = __int_as_float(c0.y) * di;
        const float w1 = __int_as_float(c1.y) * di;
        const float w2 = __int_as_float(c2.y) * di;
        const float w3 = __int_as_float(c3.y) * di;
        ax += bf2f(v0.x) * w0 + bf2f(v1.x) * w1 + bf2f(v2.x) * w2 + bf2f(v3.x) * w3;
        ay += bf2f(v0.y) * w0 + bf2f(v1.y) * w1 + bf2f(v2.y) * w2 + bf2f(v3.y) * w3;
        az += bf2f(v0.z) * w0 + bf2f(v1.z) * w1 + bf2f(v2.z) * w2 + bf2f(v3.z) * w3;
        aw += bf2f(v0.w) * w0 + bf2f(v1.w) * w1 + bf2f(v2.w) * w2 + bf2f(v3.w) * w3;
    }
    for (; e < e1; e++) {
        const int2 ce = csr[e];
        const float w = __int_as_float(ce.y) * di;
        const ushort4 v4 = *reinterpret_cast<const ushort4*>(src + (size_t)ce.x * 64 + lane * 4);
        ax += bf2f(v4.x) * w; ay += bf2f(v4.y) * w;
        az += bf2f(v4.z) * w; aw += bf2f(v4.w) * w;
    }
    const float4 b = reinterpret_cast<const float4*>(bias)[lane];
    float4 o = make_float4(ax + b.x, ay + b.y, az + b.z, aw + b.w);
    reinterpret_cast<float4*>(dst)[(size_t)c * 16 + lane] = o;
}

extern "C" void kernel_launch(void* const* d_in, const int* in_sizes, int n_in,
                              void* d_out, int out_size, void* d_ws, size_t ws_size,
                              hipStream_t stream) {
    const float* x  = (const float*)d_in[0];
    const int*   ei = (const int*)d_in[1];
    const float* ew = (const float*)d_in[2];
    const float* W1 = (const float*)d_in[3];
    const float* b1 = (const float*)d_in[4];
    const float* W2 = (const float*)d_in[5];
    const float* b2 = (const float*)d_in[6];
    const int N = in_sizes[0] / 128;
    const int E = in_sizes[1] / 2;
    const int* row = ei;
    const int* col = ei + E;

    char* w = (char*)d_ws;
    float* dinv = (float*)w;                 w += (size_t)N * 4;
    ushort* Xb  = (ushort*)w;                // bf16 X [N][128]; dead after gemm1
    ushort* Gb  = (ushort*)w;                // bf16 hw [N][64] (aliases Xb)
                                             w += (size_t)N * 256;
    ushort* Ab  = (ushort*)w;                w += (size_t)N * 256;  // bf16 xw
    ushort* Hb  = (ushort*)w;                w += (size_t)N * 256;  // bf16 h
    ushort* W1t = (ushort*)w;                w += 128 * 128 * 2;
    ushort* W2t = (ushort*)w;                w += 64 * 128 * 2;
    int* cnt    = (int*)w;                   w += (size_t)N * 4;
    int* rowptr = (int*)w;                   w += (size_t)(N + 1) * 4;
    int* partial= (int*)w;                   w += SCAN_BLOCKS * 4;
    int* rank   = (int*)w;                   w += (size_t)E * 4;
    int2* csr   = (int2*)w;
    float* out  = (float*)d_out;

    hipMemsetAsync(cnt, 0, (size_t)N * sizeof(int), stream);

    const int eb4 = (E / 4 + 255) / 256;     // 4 edges/thread
    cnt_kernel<<<eb4, 256, 0, stream>>>(col, cnt, rank, E);
    scan_part_kernel<<<SCAN_BLOCKS, 256, 0, stream>>>(cnt, partial, N);
    scan_tops_kernel<<<1, 256, 0, stream>>>(partial);
    scan_write_kernel<<<SCAN_BLOCKS, 256, 0, stream>>>(cnt, partial, rowptr, N);
    fill_kernel<<<(E + 255) / 256, 256, 0, stream>>>(row, col, ew, rowptr, rank, csr, E);
    degsum_kernel<<<(N + 255) / 256, 256, 0, stream>>>(rowptr, csr, dinv, N);

    const int nx4 = N * 32;
    const int misc_blocks = (nx4 + 255) / 256 + (E + 255) / 256 + 64 + 32;
    misc_kernel<<<misc_blocks, 256, 0, stream>>>(csr, dinv, E, x, Xb, nx4,
                                                 W1, W1t, W2, W2t);

    const int ntiles = (N + 127) / 128;

    // ---- layer 1: Hb = relu(Ahat @ (X W1) + b1)
    mfma_gemm_kernel<128, true><<<ntiles, 256, 0, stream>>>(Xb, W1t, Ab, N);
    agg1_kernel<<<(int)(((long long)N * 32 + 255) / 256), 256, 0, stream>>>(
        rowptr, csr, dinv, Ab, b1, Hb, N);

    // ---- layer 2: out = Ahat @ (Hb W2) + b2
    mfma_gemm_kernel<64, true><<<ntiles, 256, 0, stream>>>(Hb, W2t, Gb, N);
    agg2_kernel<<<(int)(((long long)N * 16 + 255) / 256), 256, 0, stream>>>(
        rowptr, csr, dinv, Gb, b2, out, N);
}

// Round 8
// 161.006 us; speedup vs baseline: 10.7128x; 1.0019x over previous
//
#include <hip/hip_runtime.h>

// 2-layer GCN: atomic-light CSR build + bf16 MFMA GEMMs + MLP-unrolled
// gather aggregation.
// Pipeline: zero(cnt) -> cnt(+rank) -> scan -> fill -> degsum/dinv ->
// misc(premult + bf16 converts) -> gemm1 -> agg1 -> gemm2 -> agg2.

constexpr int SCAN_BLOCKS = 256;

typedef __attribute__((ext_vector_type(8))) short short8;   // 8 bf16 (4 VGPR)
typedef __attribute__((ext_vector_type(4))) float f32x4;

__device__ __forceinline__ ushort f2bf(float f) {           // RNE f32->bf16
    unsigned u = __float_as_uint(f);
    return (ushort)((u + 0x7fffu + ((u >> 16) & 1u)) >> 16);
}
__device__ __forceinline__ float bf2f(ushort h) {
    return __uint_as_float((unsigned)h << 16);
}

// zero n ints (16B vectorized; rocclr fillBuffer costs ~40us, this ~4us)
__global__ void zero_kernel(int* __restrict__ p, int n) {
    const int n4 = n >> 2;
    const int i = blockIdx.x * blockDim.x + threadIdx.x;
    if (i < n4) reinterpret_cast<int4*>(p)[i] = make_int4(0, 0, 0, 0);
    if (i < (n & 3)) p[n4 * 4 + i] = 0;
}

// histogram of col[] + per-edge rank within its destination bucket
__global__ void cnt_kernel(const int* __restrict__ col, int* __restrict__ cnt,
                           int* __restrict__ rank, int E) {
    const int stride = gridDim.x * blockDim.x;
    for (int e = blockIdx.x * blockDim.x + threadIdx.x; e < E; e += stride)
        rank[e] = atomicAdd(&cnt[col[e]], 1);
}

// ---- 3-pass scan: cnt[N] -> exclusive rowptr[N+1] ----
__global__ __launch_bounds__(256) void scan_part_kernel(
        const int* __restrict__ cnt, int* __restrict__ partial, int N) {
    const int T = SCAN_BLOCKS * 256;
    const int chunk = (N + T - 1) / T;
    const int j = blockIdx.x * 256 + threadIdx.x;
    const int s = j * chunk, e = min(s + chunk, N);
    int acc = 0;
    for (int i = s; i < e; i++) acc += cnt[i];
    __shared__ int red[256];
    red[threadIdx.x] = acc;
    __syncthreads();
    for (int off = 128; off > 0; off >>= 1) {
        if (threadIdx.x < off) red[threadIdx.x] += red[threadIdx.x + off];
        __syncthreads();
    }
    if (threadIdx.x == 0) partial[blockIdx.x] = red[0];
}

__global__ __launch_bounds__(256) void scan_tops_kernel(int* __restrict__ partial) {
    __shared__ int sh[256];
    const int t = threadIdx.x;
    int v = (t < SCAN_BLOCKS) ? partial[t] : 0;
    sh[t] = v;
    __syncthreads();
    for (int off = 1; off < 256; off <<= 1) {
        int x = sh[t];
        int a = (t >= off) ? sh[t - off] : 0;
        __syncthreads();
        sh[t] = x + a;
        __syncthreads();
    }
    if (t < SCAN_BLOCKS) partial[t] = (t == 0) ? 0 : sh[t - 1];
}

__global__ __launch_bounds__(256) void scan_write_kernel(
        const int* __restrict__ cnt, const int* __restrict__ partial,
        int* __restrict__ rowptr, int N) {
    const int T = SCAN_BLOCKS * 256;
    const int chunk = (N + T - 1) / T;
    const int j = blockIdx.x * 256 + threadIdx.x;
    const int s = j * chunk, e = min(s + chunk, N);
    int acc = 0;
    for (int i = s; i < e; i++) acc += cnt[i];
    __shared__ int sh[256];
    const int t = threadIdx.x;
    sh[t] = acc;
    __syncthreads();
    for (int off = 1; off < 256; off <<= 1) {
        int x = sh[t];
        int a = (t >= off) ? sh[t - off] : 0;
        __syncthreads();
        sh[t] = x + a;
        __syncthreads();
    }
    int excl = partial[blockIdx.x] + ((t == 0) ? 0 : sh[t - 1]);
    for (int i = s; i < e; i++) {
        rowptr[i] = excl;
        excl += cnt[i];
    }
    if (j == T - 1) rowptr[N] = excl;
}

// fill CSR with {src, raw ew}; position from rowptr+rank (no atomics)
__global__ void fill_kernel(const int* __restrict__ row, const int* __restrict__ col,
        const float* __restrict__ ew, const int* __restrict__ rowptr,
        const int* __restrict__ rank, int2* __restrict__ csr, int E) {
    int e = blockIdx.x * blockDim.x + threadIdx.x;
    if (e < E) {
        const int p = rowptr[col[e]] + rank[e];
        csr[p] = make_int2(row[e], __float_as_int(ew[e]));
    }
}

// per-node degree from CSR range: dinv[n] = rsqrt(1 + sum ew)
__global__ __launch_bounds__(256) void degsum_kernel(
        const int* __restrict__ rowptr, const int2* __restrict__ csr,
        float* __restrict__ dinv, int N) {
    const int n = blockIdx.x * blockDim.x + threadIdx.x;
    if (n >= N) return;
    const int e0 = rowptr[n], e1 = rowptr[n + 1];
    float d = 1.0f;
    for (int e = e0; e < e1; e++) d += __int_as_float(csr[e].y);
    dinv[n] = (d > 0.0f) ? rsqrtf(d) : 0.0f;
}

// fused: premult csr.w *= dinv[src]  |  X->bf16  |  W1->W1t bf16  |  W2->W2t
__global__ __launch_bounds__(256) void misc_kernel(
        int2* __restrict__ csr, const float* __restrict__ dinv, int E,
        const float* __restrict__ X, ushort* __restrict__ Xb, int nx4,
        const float* __restrict__ W1, ushort* __restrict__ W1t,
        const float* __restrict__ W2, ushort* __restrict__ W2t) {
    const int nb_x = (nx4 + 255) / 256;
    const int nb_p = (E + 255) / 256;
    int b = blockIdx.x;
    if (b < nb_x) {                        // cvt X
        const int i = b * 256 + threadIdx.x;
        if (i < nx4) {
            float4 v = reinterpret_cast<const float4*>(X)[i];
            ushort4 o;
            o.x = f2bf(v.x); o.y = f2bf(v.y); o.z = f2bf(v.z); o.w = f2bf(v.w);
            reinterpret_cast<ushort4*>(Xb)[i] = o;
        }
        return;
    }
    b -= nb_x;
    if (b < nb_p) {                        // premult
        const int e = b * 256 + threadIdx.x;
        if (e < E) {
            int2 c = csr[e];
            ((float*)csr)[2 * (size_t)e + 1] = __int_as_float(c.y) * dinv[c.x];
        }
        return;
    }
    b -= nb_p;
    if (b < 64) {                          // W1t[c*128+k] = W1[k*128+c]
        const int o = b * 256 + threadIdx.x;
        W1t[o] = f2bf(W1[(size_t)(o & 127) * 128 + (o >> 7)]);
        return;
    }
    b -= 64;
    {                                      // W2t[c*128+k] = W2[k*64+c]
        const int o = b * 256 + threadIdx.x;
        if (o < 64 * 128)
            W2t[o] = f2bf(W2[(size_t)(o & 127) * 64 + (o >> 7)]);
    }
}

// MFMA GEMM: Y[N,DOUT] = Xb[N,128] @ Wt^T.  K=128 one-shot, 128-row tile,
// 4 waves, XOR-swizzled LDS (byte ^= (row&7)<<4).
template <int DOUT, bool OUT_BF16>
__global__ __launch_bounds__(256, 2) void mfma_gemm_kernel(
        const ushort* __restrict__ Xb, const ushort* __restrict__ Wt,
        void* __restrict__ Y, int N) {
    constexpr int CW = DOUT / 64;
    constexpr int RW = 4 / CW;
    constexpr int WROWS = 128 / RW;
    constexpr int MI = WROWS / 16;
    __shared__ __align__(16) ushort sX[128 * 128];
    __shared__ __align__(16) ushort sW[DOUT * 128];
    const int tid = threadIdx.x;
    const int base = blockIdx.x * 128;

    #pragma unroll
    for (int p = 0; p < 8; p++) {
        const int ch = p * 256 + tid;
        const int r = ch >> 4, cpos = ch & 15;
        const int grow = base + r;
        uint4 v = make_uint4(0, 0, 0, 0);
        if (grow < N)
            v = *reinterpret_cast<const uint4*>(Xb + (size_t)grow * 128 + cpos * 8);
        const int b = (cpos * 16) ^ ((r & 7) << 4);
        *reinterpret_cast<uint4*>(reinterpret_cast<char*>(sX) + r * 256 + b) = v;
    }
    for (int ch = tid; ch < DOUT * 16; ch += 256) {
        const int r = ch >> 4, cpos = ch & 15;
        uint4 v = *reinterpret_cast<const uint4*>(Wt + (size_t)r * 128 + cpos * 8);
        const int b = (cpos * 16) ^ ((r & 7) << 4);
        *reinterpret_cast<uint4*>(reinterpret_cast<char*>(sW) + r * 256 + b) = v;
    }
    __syncthreads();

    const int lane = tid & 63;
    const int wid = tid >> 6;
    const int wr = wid / CW;
    const int wc = wid % CW;
    const int lr = lane & 15;
    const int g  = lane >> 4;

    f32x4 acc[MI][4];
    #pragma unroll
    for (int i = 0; i < MI; i++)
        #pragma unroll
        for (int f = 0; f < 4; f++)
            acc[i][f] = (f32x4){0.f, 0.f, 0.f, 0.f};

    #pragma unroll
    for (int ks = 0; ks < 4; ks++) {
        const int koff = ks * 64 + g * 16;
        short8 a[MI], b[4];
        #pragma unroll
        for (int i = 0; i < MI; i++) {
            const int row = wr * WROWS + i * 16 + lr;
            a[i] = *reinterpret_cast<const short8*>(
                reinterpret_cast<const char*>(sX) + row * 256 + (koff ^ ((row & 7) << 4)));
        }
        #pragma unroll
        for (int f = 0; f < 4; f++) {
            const int col = wc * 64 + f * 16 + lr;
            b[f] = *reinterpret_cast<const short8*>(
                reinterpret_cast<const char*>(sW) + col * 256 + (koff ^ ((col & 7) << 4)));
        }
        #pragma unroll
        for (int i = 0; i < MI; i++)
            #pragma unroll
            for (int f = 0; f < 4; f++)
                acc[i][f] = __builtin_amdgcn_mfma_f32_16x16x32_bf16(a[i], b[f], acc[i][f], 0, 0, 0);
    }

    #pragma unroll
    for (int i = 0; i < MI; i++) {
        #pragma unroll
        for (int reg = 0; reg < 4; reg++) {
            const int grow = base + wr * WROWS + i * 16 + g * 4 + reg;
            if (grow < N) {
                #pragma unroll
                for (int f = 0; f < 4; f++) {
                    const int gcol = wc * 64 + f * 16 + lr;
                    const float v = acc[i][f][reg];
                    if (OUT_BF16)
                        ((ushort*)Y)[(size_t)grow * DOUT + gcol] = f2bf(v);
                    else
                        ((float*)Y)[(size_t)grow * DOUT + gcol] = v;
                }
            }
        }
    }
}

// Layer-1 aggregation: bf16 src, f32 accum, bf16 dst; self-loop+bias+relu.
// 32 lanes/node; 4-wide unrolled edge loop (4 gathers in flight).
__global__ __launch_bounds__(256) void agg1_kernel(
        const int* __restrict__ rowptr, const int2* __restrict__ csr,
        const float* __restrict__ dinv,
        const ushort* __restrict__ src, const float* __restrict__ bias,
        ushort* __restrict__ dst, int N) {
    const long long gid = (long long)blockIdx.x * blockDim.x + threadIdx.x;
    const int c = (int)(gid >> 5);
    if (c >= N) return;
    const int lane = (int)(gid & 31);
    const float di = dinv[c];
    const float sl = di * di;
    ushort4 s4 = *reinterpret_cast<const ushort4*>(src + (size_t)c * 128 + lane * 4);
    float ax = bf2f(s4.x) * sl, ay = bf2f(s4.y) * sl,
          az = bf2f(s4.z) * sl, aw = bf2f(s4.w) * sl;
    const int e0 = rowptr[c], e1 = rowptr[c + 1];
    int e = e0;
    for (; e + 4 <= e1; e += 4) {
        const int2 c0 = csr[e], c1 = csr[e + 1], c2 = csr[e + 2], c3 = csr[e + 3];
        const ushort4 v0 = *reinterpret_cast<const ushort4*>(src + (size_t)c0.x * 128 + lane * 4);
        const ushort4 v1 = *reinterpret_cast<const ushort4*>(src + (size_t)c1.x * 128 + lane * 4);
        const ushort4 v2 = *reinterpret_cast<const ushort4*>(src + (size_t)c2.x * 128 + lane * 4);
        const ushort4 v3 = *reinterpret_cast<const ushort4*>(src + (size_t)c3.x * 128 + lane * 4);
        const float w0 = __int_as_float(c0.y) * di;
        const float w1 = __int_as_float(c1.y) * di;
        const float w2 = __int_as_float(c2.y) * di;
        const float w3 = __int_as_float(c3.y) * di;
        ax += bf2f(v0.x) * w0 + bf2f(v1.x) * w1 + bf2f(v2.x) * w2 + bf2f(v3.x) * w3;
        ay += bf2f(v0.y) * w0 + bf2f(v1.y) * w1 + bf2f(v2.y) * w2 + bf2f(v3.y) * w3;
        az += bf2f(v0.z) * w0 + bf2f(v1.z) * w1 + bf2f(v2.z) * w2 + bf2f(v3.z) * w3;
        aw += bf2f(v0.w) * w0 + bf2f(v1.w) * w1 + bf2f(v2.w) * w2 + bf2f(v3.w) * w3;
    }
    for (; e < e1; e++) {
        const int2 ce = csr[e];
        const float w = __int_as_float(ce.y) * di;
        const ushort4 v4 = *reinterpret_cast<const ushort4*>(src + (size_t)ce.x * 128 + lane * 4);
        ax += bf2f(v4.x) * w; ay += bf2f(v4.y) * w;
        az += bf2f(v4.z) * w; aw += bf2f(v4.w) * w;
    }
    const float4 b = reinterpret_cast<const float4*>(bias)[lane];
    ax = fmaxf(ax + b.x, 0.f); ay = fmaxf(ay + b.y, 0.f);
    az = fmaxf(az + b.z, 0.f); aw = fmaxf(aw + b.w, 0.f);
    ushort4 o;
    o.x = f2bf(ax); o.y = f2bf(ay); o.z = f2bf(az); o.w = f2bf(aw);
    *reinterpret_cast<ushort4*>(dst + (size_t)c * 128 + lane * 4) = o;
}

// Layer-2 aggregation: bf16 src (hw), f32 accum, f32 out; 16 lanes/node.
__global__ __launch_bounds__(256) void agg2_kernel(
        const int* __restrict__ rowptr, const int2* __restrict__ csr,
        const float* __restrict__ dinv,
        const ushort* __restrict__ src, const float* __restrict__ bias,
        float* __restrict__ dst, int N) {
    const long long gid = (long long)blockIdx.x * blockDim.x + threadIdx.x;
    const int c = (int)(gid >> 4);
    if (c >= N) return;
    const int lane = (int)(gid & 15);
    const float di = dinv[c];
    const float sl = di * di;
    ushort4 s4 = *reinterpret_cast<const ushort4*>(src + (size_t)c * 64 + lane * 4);
    float ax = bf2f(s4.x) * sl, ay = bf2f(s4.y) * sl,
          az = bf2f(s4.z) * sl, aw = bf2f(s4.w) * sl;
    const int e0 = rowptr[c], e1 = rowptr[c + 1];
    int e = e0;
    for (; e + 4 <= e1; e += 4) {
        const int2 c0 = csr[e], c1 = csr[e + 1], c2 = csr[e + 2], c3 = csr[e + 3];
        const ushort4 v0 = *reinterpret_cast<const ushort4*>(src + (size_t)c0.x * 64 + lane * 4);
        const ushort4 v1 = *reinterpret_cast<const ushort4*>(src + (size_t)c1.x * 64 + lane * 4);
        const ushort4 v2 = *reinterpret_cast<const ushort4*>(src + (size_t)c2.x * 64 + lane * 4);
        const ushort4 v3 = *reinterpret_cast<const ushort4*>(src + (size_t)c3.x * 64 + lane * 4);
        const float w0 = __int_as_float(c0.y) * di;
        const float w1 = __int_as_float(c1.y) * di;
        const float w2 = __int_as_float(c2.y) * di;
        const float w3 = __int_as_float(c3.y) * di;
        ax += bf2f(v0.x) * w0 + bf2f(v1.x) * w1 + bf2f(v2.x) * w2 + bf2f(v3.x) * w3;
        ay += bf2f(v0.y) * w0 + bf2f(v1.y) * w1 + bf2f(v2.y) * w2 + bf2f(v3.y) * w3;
        az += bf2f(v0.z) * w0 + bf2f(v1.z) * w1 + bf2f(v2.z) * w2 + bf2f(v3.z) * w3;
        aw += bf2f(v0.w) * w0 + bf2f(v1.w) * w1 + bf2f(v2.w) * w2 + bf2f(v3.w) * w3;
    }
    for (; e < e1; e++) {
        const int2 ce = csr[e];
        const float w = __int_as_float(ce.y) * di;
        const ushort4 v4 = *reinterpret_cast<const ushort4*>(src + (size_t)ce.x * 64 + lane * 4);
        ax += bf2f(v4.x) * w; ay += bf2f(v4.y) * w;
        az += bf2f(v4.z) * w; aw += bf2f(v4.w) * w;
    }
    const float4 b = reinterpret_cast<const float4*>(bias)[lane];
    float4 o = make_float4(ax + b.x, ay + b.y, az + b.z, aw + b.w);
    reinterpret_cast<float4*>(dst)[(size_t)c * 16 + lane] = o;
}

extern "C" void kernel_launch(void* const* d_in, const int* in_sizes, int n_in,
                              void* d_out, int out_size, void* d_ws, size_t ws_size,
                              hipStream_t stream) {
    const float* x  = (const float*)d_in[0];
    const int*   ei = (const int*)d_in[1];
    const float* ew = (const float*)d_in[2];
    const float* W1 = (const float*)d_in[3];
    const float* b1 = (const float*)d_in[4];
    const float* W2 = (const float*)d_in[5];
    const float* b2 = (const float*)d_in[6];
    const int N = in_sizes[0] / 128;
    const int E = in_sizes[1] / 2;
    const int* row = ei;
    const int* col = ei + E;

    char* w = (char*)d_ws;
    float* dinv = (float*)w;                 w += (size_t)N * 4;
    ushort* Xb  = (ushort*)w;                // bf16 X [N][128]; dead after gemm1
    ushort* Gb  = (ushort*)w;                // bf16 hw [N][64] (aliases Xb)
                                             w += (size_t)N * 256;
    ushort* Ab  = (ushort*)w;                w += (size_t)N * 256;  // bf16 xw
    ushort* Hb  = (ushort*)w;                w += (size_t)N * 256;  // bf16 h
    ushort* W1t = (ushort*)w;                w += 128 * 128 * 2;
    ushort* W2t = (ushort*)w;                w += 64 * 128 * 2;
    int* cnt    = (int*)w;                   w += (size_t)N * 4;
    int* rowptr = (int*)w;                   w += (size_t)(N + 1) * 4;
    int* partial= (int*)w;                   w += SCAN_BLOCKS * 4;
    int* rank   = (int*)w;                   w += (size_t)E * 4;
    int2* csr   = (int2*)w;
    float* out  = (float*)d_out;

    zero_kernel<<<(N / 4 + 255) / 256, 256, 0, stream>>>(cnt, N);

    const int eb4 = (E / 4 + 255) / 256;     // 4 edges/thread
    cnt_kernel<<<eb4, 256, 0, stream>>>(col, cnt, rank, E);
    scan_part_kernel<<<SCAN_BLOCKS, 256, 0, stream>>>(cnt, partial, N);
    scan_tops_kernel<<<1, 256, 0, stream>>>(partial);
    scan_write_kernel<<<SCAN_BLOCKS, 256, 0, stream>>>(cnt, partial, rowptr, N);
    fill_kernel<<<(E + 255) / 256, 256, 0, stream>>>(row, col, ew, rowptr, rank, csr, E);
    degsum_kernel<<<(N + 255) / 256, 256, 0, stream>>>(rowptr, csr, dinv, N);

    const int nx4 = N * 32;
    const int misc_blocks = (nx4 + 255) / 256 + (E + 255) / 256 + 64 + 32;
    misc_kernel<<<misc_blocks, 256, 0, stream>>>(csr, dinv, E, x, Xb, nx4,
                                                 W1, W1t, W2, W2t);

    const int ntiles = (N + 127) / 128;

    // ---- layer 1: Hb = relu(Ahat @ (X W1) + b1)
    mfma_gemm_kernel<128, true><<<ntiles, 256, 0, stream>>>(Xb, W1t, Ab, N);
    agg1_kernel<<<(int)(((long long)N * 32 + 255) / 256), 256, 0, stream>>>(
        rowptr, csr, dinv, Ab, b1, Hb, N);

    // ---- layer 2: out = Ahat @ (Hb W2) + b2
    mfma_gemm_kernel<64, true><<<ntiles, 256, 0, stream>>>(Hb, W2t, Gb, N);
    agg2_kernel<<<(int)(((long long)N * 16 + 255) / 256), 256, 0, stream>>>(
        rowptr, csr, dinv, Gb, b2, out, N);
}

// Round 9
// 131.046 us; speedup vs baseline: 13.1620x; 1.2286x over previous
//
#include <hip/hip_runtime.h>

// 2-layer GCN: CSR gather formulation, bf16 MFMA GEMMs, fused launches.
// prep(zero+Wcvt) -> combo1(gemm1 || cnt) -> scan_part -> scan_write(+tops)
// -> fill -> degsum -> agg1 -> gemm2 -> agg2      (9 launches)

constexpr int SCAN_BLOCKS = 256;

typedef __attribute__((ext_vector_type(8))) short short8;   // 8 bf16
typedef __attribute__((ext_vector_type(4))) float f32x4;

__device__ __forceinline__ ushort f2bf(float f) {           // RNE f32->bf16
    unsigned u = __float_as_uint(f);
    return (ushort)((u + 0x7fffu + ((u >> 16) & 1u)) >> 16);
}
__device__ __forceinline__ float bf2f(ushort h) {
    return __uint_as_float((unsigned)h << 16);
}

// prep: zero cnt[N] (16B stores) | W1->W1t bf16 | W2->W2t bf16
__global__ __launch_bounds__(256) void prep_kernel(
        int* __restrict__ cnt, int N,
        const float* __restrict__ W1, ushort* __restrict__ W1t,
        const float* __restrict__ W2, ushort* __restrict__ W2t) {
    const int n4c = (N + 3) >> 2;
    const int nbz = (n4c + 255) / 256;
    int b = blockIdx.x;
    if (b < nbz) {
        const int i = b * 256 + threadIdx.x;
        if (i < n4c) reinterpret_cast<int4*>(cnt)[i] = make_int4(0, 0, 0, 0);
        return;
    }
    b -= nbz;
    if (b < 64) {                          // W1t[c*128+k] = W1[k*128+c]
        const int o = b * 256 + threadIdx.x;
        W1t[o] = f2bf(W1[(size_t)(o & 127) * 128 + (o >> 7)]);
        return;
    }
    b -= 64;
    {                                      // W2t[c*128+k] = W2[k*64+c]
        const int o = b * 256 + threadIdx.x;
        if (o < 64 * 128)
            W2t[o] = f2bf(W2[(size_t)(o & 127) * 64 + (o >> 7)]);
    }
}

// combo1: blocks [0,G) = gemm1 (f32 X staged->bf16 LDS, MFMA, bf16 out);
//         blocks [G,..) = cnt histogram + rank (latency-bound, runs alongside)
__global__ __launch_bounds__(256, 2) void combo1_kernel(
        const float* __restrict__ X, const ushort* __restrict__ W1t,
        ushort* __restrict__ Ab, int N, int G,
        const int* __restrict__ col, int* __restrict__ cnt,
        int* __restrict__ rank, int E) {
    __shared__ __align__(16) ushort sX[128 * 128];
    __shared__ __align__(16) ushort sW[128 * 128];
    const int tid = threadIdx.x;

    if (blockIdx.x >= G) {    // ---- cnt branch ----
        const int T = (gridDim.x - G) * 256;
        for (int e = (blockIdx.x - G) * 256 + tid; e < E; e += T)
            rank[e] = atomicAdd(&cnt[col[e]], 1);
        return;
    }

    // ---- gemm1 branch (DOUT=128: CW=2 col-waves, WROWS=64, MI=4) ----
    const int base = blockIdx.x * 128;
    #pragma unroll
    for (int p = 0; p < 8; p++) {         // stage X f32 -> bf16, swizzled
        const int ch = p * 256 + tid;     // 2048 chunks of 8 elems
        const int r = ch >> 4, cpos = ch & 15;
        const int grow = base + r;
        uint4 u = make_uint4(0, 0, 0, 0);
        if (grow < N) {
            const float* xp = X + (size_t)grow * 128 + cpos * 8;
            const float4 a = *reinterpret_cast<const float4*>(xp);
            const float4 c = *reinterpret_cast<const float4*>(xp + 4);
            u.x = (uint)f2bf(a.x) | ((uint)f2bf(a.y) << 16);
            u.y = (uint)f2bf(a.z) | ((uint)f2bf(a.w) << 16);
            u.z = (uint)f2bf(c.x) | ((uint)f2bf(c.y) << 16);
            u.w = (uint)f2bf(c.z) | ((uint)f2bf(c.w) << 16);
        }
        const int b = (cpos * 16) ^ ((r & 7) << 4);
        *reinterpret_cast<uint4*>(reinterpret_cast<char*>(sX) + r * 256 + b) = u;
    }
    #pragma unroll
    for (int p = 0; p < 8; p++) {         // stage W1t (bf16), swizzled
        const int ch = p * 256 + tid;
        const int r = ch >> 4, cpos = ch & 15;
        uint4 v = *reinterpret_cast<const uint4*>(W1t + (size_t)r * 128 + cpos * 8);
        const int b = (cpos * 16) ^ ((r & 7) << 4);
        *reinterpret_cast<uint4*>(reinterpret_cast<char*>(sW) + r * 256 + b) = v;
    }
    __syncthreads();

    const int lane = tid & 63;
    const int wid = tid >> 6;
    const int wr = wid >> 1;              // 2 row-waves
    const int wc = wid & 1;               // 2 col-waves
    const int lr = lane & 15;
    const int g  = lane >> 4;

    f32x4 acc[4][4];
    #pragma unroll
    for (int i = 0; i < 4; i++)
        #pragma unroll
        for (int f = 0; f < 4; f++) acc[i][f] = (f32x4){0.f, 0.f, 0.f, 0.f};

    #pragma unroll
    for (int ks = 0; ks < 4; ks++) {
        const int koff = ks * 64 + g * 16;
        short8 a[4], b[4];
        #pragma unroll
        for (int i = 0; i < 4; i++) {
            const int row = wr * 64 + i * 16 + lr;
            a[i] = *reinterpret_cast<const short8*>(
                reinterpret_cast<const char*>(sX) + row * 256 + (koff ^ ((row & 7) << 4)));
        }
        #pragma unroll
        for (int f = 0; f < 4; f++) {
            const int c = wc * 64 + f * 16 + lr;
            b[f] = *reinterpret_cast<const short8*>(
                reinterpret_cast<const char*>(sW) + c * 256 + (koff ^ ((c & 7) << 4)));
        }
        #pragma unroll
        for (int i = 0; i < 4; i++)
            #pragma unroll
            for (int f = 0; f < 4; f++)
                acc[i][f] = __builtin_amdgcn_mfma_f32_16x16x32_bf16(a[i], b[f], acc[i][f], 0, 0, 0);
    }

    #pragma unroll
    for (int i = 0; i < 4; i++)
        #pragma unroll
        for (int reg = 0; reg < 4; reg++) {
            const int grow = base + wr * 64 + i * 16 + g * 4 + reg;
            if (grow < N)
                #pragma unroll
                for (int f = 0; f < 4; f++)
                    Ab[(size_t)grow * 128 + wc * 64 + f * 16 + lr] = f2bf(acc[i][f][reg]);
        }
}

// scan pass 1: per-block sums
__global__ __launch_bounds__(256) void scan_part_kernel(
        const int* __restrict__ cnt, int* __restrict__ partial, int N) {
    const int T = SCAN_BLOCKS * 256;
    const int chunk = (N + T - 1) / T;
    const int j = blockIdx.x * 256 + threadIdx.x;
    const int s = j * chunk, e = min(s + chunk, N);
    int acc = 0;
    for (int i = s; i < e; i++) acc += cnt[i];
    __shared__ int red[256];
    red[threadIdx.x] = acc;
    __syncthreads();
    for (int off = 128; off > 0; off >>= 1) {
        if (threadIdx.x < off) red[threadIdx.x] += red[threadIdx.x + off];
        __syncthreads();
    }
    if (threadIdx.x == 0) partial[blockIdx.x] = red[0];
}

// scan pass 2: each block scans the 256 partials in LDS (inline tops) and
// writes its rowptr chunk.
__global__ __launch_bounds__(256) void scan_write_kernel(
        const int* __restrict__ cnt, const int* __restrict__ partial,
        int* __restrict__ rowptr, int N) {
    __shared__ int tp[256];
    __shared__ int sh[256];
    const int t = threadIdx.x;
    tp[t] = partial[t];
    __syncthreads();
    for (int off = 1; off < 256; off <<= 1) {
        int x = tp[t];
        int a = (t >= off) ? tp[t - off] : 0;
        __syncthreads();
        tp[t] = x + a;
        __syncthreads();
    }
    const int blockOff = (blockIdx.x == 0) ? 0 : tp[blockIdx.x - 1];

    const int T = SCAN_BLOCKS * 256;
    const int chunk = (N + T - 1) / T;
    const int j = blockIdx.x * 256 + t;
    const int s = j * chunk, e = min(s + chunk, N);
    int acc = 0;
    for (int i = s; i < e; i++) acc += cnt[i];
    sh[t] = acc;
    __syncthreads();
    for (int off = 1; off < 256; off <<= 1) {
        int x = sh[t];
        int a = (t >= off) ? sh[t - off] : 0;
        __syncthreads();
        sh[t] = x + a;
        __syncthreads();
    }
    int excl = blockOff + ((t == 0) ? 0 : sh[t - 1]);
    for (int i = s; i < e; i++) {
        rowptr[i] = excl;
        excl += cnt[i];
    }
    if (j == T - 1) rowptr[N] = excl;
}

// fill CSR {src, raw ew}; position = rowptr[col]+rank (no atomics)
__global__ void fill_kernel(const int* __restrict__ row, const int* __restrict__ col,
        const float* __restrict__ ew, const int* __restrict__ rowptr,
        const int* __restrict__ rank, int2* __restrict__ csr, int E) {
    int e = blockIdx.x * blockDim.x + threadIdx.x;
    if (e < E) {
        const int p = rowptr[col[e]] + rank[e];
        csr[p] = make_int2(row[e], __float_as_int(ew[e]));
    }
}

// dinv[n] = rsqrt(1 + sum of raw ew over CSR range)
__global__ __launch_bounds__(256) void degsum_kernel(
        const int* __restrict__ rowptr, const int2* __restrict__ csr,
        float* __restrict__ dinv, int N) {
    const int n = blockIdx.x * blockDim.x + threadIdx.x;
    if (n >= N) return;
    const int e0 = rowptr[n], e1 = rowptr[n + 1];
    float d = 1.0f;
    for (int e = e0; e < e1; e++) d += __int_as_float(csr[e].y);
    dinv[n] = (d > 0.0f) ? rsqrtf(d) : 0.0f;
}

// Layer-1 agg: 16 lanes/node, short8 (16B) loads; w = ew*dinv[src]*dinv[c];
// fused self-loop + bias + relu; bf16 in/out, f32 accum.
__global__ __launch_bounds__(256) void agg1_kernel(
        const int* __restrict__ rowptr, const int2* __restrict__ csr,
        const float* __restrict__ dinv,
        const ushort* __restrict__ src, const float* __restrict__ bias,
        ushort* __restrict__ dst, int N) {
    const long long gid = (long long)blockIdx.x * blockDim.x + threadIdx.x;
    const int c = (int)(gid >> 4);
    if (c >= N) return;
    const int lane = (int)(gid & 15);
    const float di = dinv[c];
    const float sl = di * di;
    float acc[8];
    {
        const short8 s8 = *reinterpret_cast<const short8*>(src + (size_t)c * 128 + lane * 8);
        #pragma unroll
        for (int j = 0; j < 8; j++) acc[j] = bf2f((ushort)s8[j]) * sl;
    }
    const int e0 = rowptr[c], e1 = rowptr[c + 1];
    int e = e0;
    for (; e + 4 <= e1; e += 4) {
        const int2 c0 = csr[e], c1 = csr[e + 1], c2 = csr[e + 2], c3 = csr[e + 3];
        const float w0 = __int_as_float(c0.y) * dinv[c0.x] * di;
        const float w1 = __int_as_float(c1.y) * dinv[c1.x] * di;
        const float w2 = __int_as_float(c2.y) * dinv[c2.x] * di;
        const float w3 = __int_as_float(c3.y) * dinv[c3.x] * di;
        const short8 v0 = *reinterpret_cast<const short8*>(src + (size_t)c0.x * 128 + lane * 8);
        const short8 v1 = *reinterpret_cast<const short8*>(src + (size_t)c1.x * 128 + lane * 8);
        const short8 v2 = *reinterpret_cast<const short8*>(src + (size_t)c2.x * 128 + lane * 8);
        const short8 v3 = *reinterpret_cast<const short8*>(src + (size_t)c3.x * 128 + lane * 8);
        #pragma unroll
        for (int j = 0; j < 8; j++)
            acc[j] += bf2f((ushort)v0[j]) * w0 + bf2f((ushort)v1[j]) * w1 +
                      bf2f((ushort)v2[j]) * w2 + bf2f((ushort)v3[j]) * w3;
    }
    for (; e < e1; e++) {
        const int2 ce = csr[e];
        const float w = __int_as_float(ce.y) * dinv[ce.x] * di;
        const short8 v = *reinterpret_cast<const short8*>(src + (size_t)ce.x * 128 + lane * 8);
        #pragma unroll
        for (int j = 0; j < 8; j++) acc[j] += bf2f((ushort)v[j]) * w;
    }
    const float4 b0 = reinterpret_cast<const float4*>(bias)[lane * 2];
    const float4 b1 = reinterpret_cast<const float4*>(bias)[lane * 2 + 1];
    acc[0] = fmaxf(acc[0] + b0.x, 0.f); acc[1] = fmaxf(acc[1] + b0.y, 0.f);
    acc[2] = fmaxf(acc[2] + b0.z, 0.f); acc[3] = fmaxf(acc[3] + b0.w, 0.f);
    acc[4] = fmaxf(acc[4] + b1.x, 0.f); acc[5] = fmaxf(acc[5] + b1.y, 0.f);
    acc[6] = fmaxf(acc[6] + b1.z, 0.f); acc[7] = fmaxf(acc[7] + b1.w, 0.f);
    uint4 o;
    o.x = (uint)f2bf(acc[0]) | ((uint)f2bf(acc[1]) << 16);
    o.y = (uint)f2bf(acc[2]) | ((uint)f2bf(acc[3]) << 16);
    o.z = (uint)f2bf(acc[4]) | ((uint)f2bf(acc[5]) << 16);
    o.w = (uint)f2bf(acc[6]) | ((uint)f2bf(acc[7]) << 16);
    *reinterpret_cast<uint4*>(dst + (size_t)c * 128 + lane * 8) = o;
}

// Layer-2 agg: 8 lanes/node, short8 loads from bf16 hw; f32 out + bias.
__global__ __launch_bounds__(256) void agg2_kernel(
        const int* __restrict__ rowptr, const int2* __restrict__ csr,
        const float* __restrict__ dinv,
        const ushort* __restrict__ src, const float* __restrict__ bias,
        float* __restrict__ dst, int N) {
    const long long gid = (long long)blockIdx.x * blockDim.x + threadIdx.x;
    const int c = (int)(gid >> 3);
    if (c >= N) return;
    const int lane = (int)(gid & 7);
    const float di = dinv[c];
    const float sl = di * di;
    float acc[8];
    {
        const short8 s8 = *reinterpret_cast<const short8*>(src + (size_t)c * 64 + lane * 8);
        #pragma unroll
        for (int j = 0; j < 8; j++) acc[j] = bf2f((ushort)s8[j]) * sl;
    }
    const int e0 = rowptr[c], e1 = rowptr[c + 1];
    int e = e0;
    for (; e + 4 <= e1; e += 4) {
        const int2 c0 = csr[e], c1 = csr[e + 1], c2 = csr[e + 2], c3 = csr[e + 3];
        const float w0 = __int_as_float(c0.y) * dinv[c0.x] * di;
        const float w1 = __int_as_float(c1.y) * dinv[c1.x] * di;
        const float w2 = __int_as_float(c2.y) * dinv[c2.x] * di;
        const float w3 = __int_as_float(c3.y) * dinv[c3.x] * di;
        const short8 v0 = *reinterpret_cast<const short8*>(src + (size_t)c0.x * 64 + lane * 8);
        const short8 v1 = *reinterpret_cast<const short8*>(src + (size_t)c1.x * 64 + lane * 8);
        const short8 v2 = *reinterpret_cast<const short8*>(src + (size_t)c2.x * 64 + lane * 8);
        const short8 v3 = *reinterpret_cast<const short8*>(src + (size_t)c3.x * 64 + lane * 8);
        #pragma unroll
        for (int j = 0; j < 8; j++)
            acc[j] += bf2f((ushort)v0[j]) * w0 + bf2f((ushort)v1[j]) * w1 +
                      bf2f((ushort)v2[j]) * w2 + bf2f((ushort)v3[j]) * w3;
    }
    for (; e < e1; e++) {
        const int2 ce = csr[e];
        const float w = __int_as_float(ce.y) * dinv[ce.x] * di;
        const short8 v = *reinterpret_cast<const short8*>(src + (size_t)ce.x * 64 + lane * 8);
        #pragma unroll
        for (int j = 0; j < 8; j++) acc[j] += bf2f((ushort)v[j]) * w;
    }
    const float4 b0 = reinterpret_cast<const float4*>(bias)[lane * 2];
    const float4 b1 = reinterpret_cast<const float4*>(bias)[lane * 2 + 1];
    float* dp = dst + (size_t)c * 64 + lane * 8;
    *reinterpret_cast<float4*>(dp) =
        make_float4(acc[0] + b0.x, acc[1] + b0.y, acc[2] + b0.z, acc[3] + b0.w);
    *reinterpret_cast<float4*>(dp + 4) =
        make_float4(acc[4] + b1.x, acc[5] + b1.y, acc[6] + b1.z, acc[7] + b1.w);
}

// Layer-2 GEMM (bf16 in, bf16 out): same structure as combo1's gemm, DOUT=64.
__global__ __launch_bounds__(256, 2) void gemm2_kernel(
        const ushort* __restrict__ Xb, const ushort* __restrict__ Wt,
        ushort* __restrict__ Y, int N) {
    __shared__ __align__(16) ushort sX[128 * 128];
    __shared__ __align__(16) ushort sW[64 * 128];
    const int tid = threadIdx.x;
    const int base = blockIdx.x * 128;

    #pragma unroll
    for (int p = 0; p < 8; p++) {
        const int ch = p * 256 + tid;
        const int r = ch >> 4, cpos = ch & 15;
        const int grow = base + r;
        uint4 v = make_uint4(0, 0, 0, 0);
        if (grow < N)
            v = *reinterpret_cast<const uint4*>(Xb + (size_t)grow * 128 + cpos * 8);
        const int b = (cpos * 16) ^ ((r & 7) << 4);
        *reinterpret_cast<uint4*>(reinterpret_cast<char*>(sX) + r * 256 + b) = v;
    }
    #pragma unroll
    for (int p = 0; p < 4; p++) {
        const int ch = p * 256 + tid;
        const int r = ch >> 4, cpos = ch & 15;
        uint4 v = *reinterpret_cast<const uint4*>(Wt + (size_t)r * 128 + cpos * 8);
        const int b = (cpos * 16) ^ ((r & 7) << 4);
        *reinterpret_cast<uint4*>(reinterpret_cast<char*>(sW) + r * 256 + b) = v;
    }
    __syncthreads();

    const int lane = tid & 63;
    const int wid = tid >> 6;           // 4 row-waves, 1 col-wave
    const int lr = lane & 15;
    const int g  = lane >> 4;

    f32x4 acc[2][4];
    #pragma unroll
    for (int i = 0; i < 2; i++)
        #pragma unroll
        for (int f = 0; f < 4; f++) acc[i][f] = (f32x4){0.f, 0.f, 0.f, 0.f};

    #pragma unroll
    for (int ks = 0; ks < 4; ks++) {
        const int koff = ks * 64 + g * 16;
        short8 a[2], b[4];
        #pragma unroll
        for (int i = 0; i < 2; i++) {
            const int row = wid * 32 + i * 16 + lr;
            a[i] = *reinterpret_cast<const short8*>(
                reinterpret_cast<const char*>(sX) + row * 256 + (koff ^ ((row & 7) << 4)));
        }
        #pragma unroll
        for (int f = 0; f < 4; f++) {
            const int c = f * 16 + lr;
            b[f] = *reinterpret_cast<const short8*>(
                reinterpret_cast<const char*>(sW) + c * 256 + (koff ^ ((c & 7) << 4)));
        }
        #pragma unroll
        for (int i = 0; i < 2; i++)
            #pragma unroll
            for (int f = 0; f < 4; f++)
                acc[i][f] = __builtin_amdgcn_mfma_f32_16x16x32_bf16(a[i], b[f], acc[i][f], 0, 0, 0);
    }

    #pragma unroll
    for (int i = 0; i < 2; i++)
        #pragma unroll
        for (int reg = 0; reg < 4; reg++) {
            const int grow = base + wid * 32 + i * 16 + g * 4 + reg;
            if (grow < N)
                #pragma unroll
                for (int f = 0; f < 4; f++)
                    Y[(size_t)grow * 64 + f * 16 + lr] = f2bf(acc[i][f][reg]);
        }
}

extern "C" void kernel_launch(void* const* d_in, const int* in_sizes, int n_in,
                              void* d_out, int out_size, void* d_ws, size_t ws_size,
                              hipStream_t stream) {
    const float* x  = (const float*)d_in[0];
    const int*   ei = (const int*)d_in[1];
    const float* ew = (const float*)d_in[2];
    const float* W1 = (const float*)d_in[3];
    const float* b1 = (const float*)d_in[4];
    const float* W2 = (const float*)d_in[5];
    const float* b2 = (const float*)d_in[6];
    const int N = in_sizes[0] / 128;
    const int E = in_sizes[1] / 2;
    const int* row = ei;
    const int* col = ei + E;

    char* w = (char*)d_ws;
    float* dinv = (float*)w;                 w += (size_t)N * 4;
    ushort* Ab  = (ushort*)w;                w += (size_t)N * 256;  // bf16 xw
    ushort* Hb  = (ushort*)w;                w += (size_t)N * 256;  // bf16 h
    ushort* Gb  = (ushort*)w;                w += (size_t)N * 128;  // bf16 hw
    ushort* W1t = (ushort*)w;                w += 128 * 128 * 2;
    ushort* W2t = (ushort*)w;                w += 64 * 128 * 2;
    int* cnt    = (int*)w;                   w += (size_t)N * 4 + 16;  // +pad
    int* rowptr = (int*)w;                   w += (size_t)(N + 1) * 4;
    int* partial= (int*)w;                   w += SCAN_BLOCKS * 4;
    int* rank   = (int*)w;                   w += (size_t)E * 4;
    int2* csr   = (int2*)w;
    float* out  = (float*)d_out;

    const int ntiles = (N + 127) / 128;
    const int nbz = (((N + 3) >> 2) + 255) / 256;

    prep_kernel<<<nbz + 64 + 32, 256, 0, stream>>>(cnt, N, W1, W1t, W2, W2t);

    const int cntb = (E / 4 + 255) / 256;    // ~4 edges/thread, grid-strided
    combo1_kernel<<<ntiles + cntb, 256, 0, stream>>>(x, W1t, Ab, N, ntiles,
                                                     col, cnt, rank, E);

    scan_part_kernel<<<SCAN_BLOCKS, 256, 0, stream>>>(cnt, partial, N);
    scan_write_kernel<<<SCAN_BLOCKS, 256, 0, stream>>>(cnt, partial, rowptr, N);
    fill_kernel<<<(E + 255) / 256, 256, 0, stream>>>(row, col, ew, rowptr, rank, csr, E);
    degsum_kernel<<<(N + 255) / 256, 256, 0, stream>>>(rowptr, csr, dinv, N);

    // ---- layer 1 finish: Hb = relu(Ahat @ Ab + b1)
    agg1_kernel<<<(int)(((long long)N * 16 + 255) / 256), 256, 0, stream>>>(
        rowptr, csr, dinv, Ab, b1, Hb, N);

    // ---- layer 2: out = Ahat @ (Hb W2) + b2
    gemm2_kernel<<<ntiles, 256, 0, stream>>>(Hb, W2t, Gb, N);
    agg2_kernel<<<(int)(((long long)N * 8 + 255) / 256), 256, 0, stream>>>(
        rowptr, csr, dinv, Gb, b2, out, N);
}